// Round 1
// baseline (11956.326 us; speedup 1.0000x reference)
//
#include <hip/hip_runtime.h>
#include <hip/hip_bf16.h>

#define NN   100000
#define NE   1600000
#define FIN  128
#define FHID 256
#define FOUT 128

// ---------------- degree ----------------
__global__ __launch_bounds__(256) void deg_kernel(const int* __restrict__ tgt,
                                                  float* __restrict__ deg) {
    int e = blockIdx.x * blockDim.x + threadIdx.x;
    if (e < NE) atomicAdd(&deg[tgt[e]], 1.0f);
}

// ---------------- scatter-add of 128-wide rows ----------------
// one thread per (edge, 4-float chunk): float4 gather + 4 atomic adds
__global__ __launch_bounds__(256) void scatter128(const float* __restrict__ xin,
                                                  const int* __restrict__ src,
                                                  const int* __restrict__ tgt,
                                                  float* __restrict__ agg) {
    long long idx = (long long)blockIdx.x * blockDim.x + threadIdx.x;
    if (idx >= (long long)NE * 32) return;
    int e = (int)(idx >> 5);
    int c = ((int)idx & 31) * 4;
    int s = src[e], t = tgt[e];
    float4 v = *(const float4*)(&xin[(long long)s * FIN + c]);
    float* a = &agg[(long long)t * FIN + c];
    atomicAdd(a + 0, v.x);
    atomicAdd(a + 1, v.y);
    atomicAdd(a + 2, v.z);
    atomicAdd(a + 3, v.w);
}

// ---------------- conv1: h = l2norm(mean@W1l.T + b1l + x@W1r.T) ----------------
// one block of 256 threads per node; thread t computes output channel t
__global__ __launch_bounds__(256) void conv1_kernel(const float* __restrict__ agg,
                                                    const float* __restrict__ deg,
                                                    const float* __restrict__ x,
                                                    const float* __restrict__ W1l,
                                                    const float* __restrict__ b1l,
                                                    const float* __restrict__ W1r,
                                                    float* __restrict__ h) {
    int node = blockIdx.x;
    int t = threadIdx.x;
    __shared__ float mrow[FIN];
    __shared__ float xrow[FIN];
    __shared__ float red[FHID];

    float invd = 1.0f / fmaxf(deg[node], 1.0f);
    if (t < FIN) {
        mrow[t] = agg[(long long)node * FIN + t] * invd;
        xrow[t] = x[(long long)node * FIN + t];
    }
    __syncthreads();

    float acc = b1l[t];
    const float* wl = &W1l[t * FIN];
    const float* wr = &W1r[t * FIN];
#pragma unroll 8
    for (int k = 0; k < FIN; ++k) acc += wl[k] * mrow[k] + wr[k] * xrow[k];

    red[t] = acc * acc;
    __syncthreads();
    for (int s = FHID / 2; s > 0; s >>= 1) {
        if (t < s) red[t] += red[t + s];
        __syncthreads();
    }
    float rn = 1.0f / fmaxf(sqrtf(red[0]), 1e-12f);
    h[(long long)node * FHID + t] = acc * rn;
}

// ---------------- linear + relu: hr = relu(h@Wlin.T + blin) ----------------
__global__ __launch_bounds__(128) void linrelu_kernel(const float* __restrict__ h,
                                                      const float* __restrict__ Wlin,
                                                      const float* __restrict__ blin,
                                                      float* __restrict__ hr) {
    int node = blockIdx.x;
    int t = threadIdx.x;
    __shared__ float hrow[FHID];
    hrow[t]       = h[(long long)node * FHID + t];
    hrow[t + 128] = h[(long long)node * FHID + t + 128];
    __syncthreads();

    float acc = blin[t];
    const float* w = &Wlin[t * FHID];
#pragma unroll 8
    for (int k = 0; k < FHID; ++k) acc += w[k] * hrow[k];
    hr[(long long)node * FOUT + t] = fmaxf(acc, 0.0f);
}

// ---------------- conv2 + linear2 + softmax (fused) ----------------
// block of 128 per node: y then two logits by reduction, softmax
__global__ __launch_bounds__(128) void conv2_kernel(const float* __restrict__ agg,
                                                    const float* __restrict__ deg,
                                                    const float* __restrict__ hr,
                                                    const float* __restrict__ W2l,
                                                    const float* __restrict__ b2l,
                                                    const float* __restrict__ W2r,
                                                    const float* __restrict__ Wlin2,
                                                    const float* __restrict__ blin2,
                                                    float* __restrict__ probs,
                                                    float* __restrict__ y) {
    int node = blockIdx.x;
    int t = threadIdx.x;
    __shared__ float mrow[FOUT];
    __shared__ float xrow[FOUT];
    __shared__ float red[FOUT];

    float invd = 1.0f / fmaxf(deg[node], 1.0f);
    mrow[t] = agg[(long long)node * FOUT + t] * invd;
    xrow[t] = hr[(long long)node * FOUT + t];
    __syncthreads();

    float acc = b2l[t];
    const float* wl = &W2l[t * FOUT];
    const float* wr = &W2r[t * FOUT];
#pragma unroll 8
    for (int k = 0; k < FOUT; ++k) acc += wl[k] * mrow[k] + wr[k] * xrow[k];

    red[t] = acc * acc;
    __syncthreads();
    for (int s = FOUT / 2; s > 0; s >>= 1) {
        if (t < s) red[t] += red[t + s];
        __syncthreads();
    }
    float rn = 1.0f / fmaxf(sqrtf(red[0]), 1e-12f);
    float yv = acc * rn;
    y[(long long)node * FOUT + t] = yv;
    __syncthreads();  // everyone has read red[0]; safe to reuse red

    // logit 0
    red[t] = yv * Wlin2[t];
    __syncthreads();
    for (int s = FOUT / 2; s > 0; s >>= 1) {
        if (t < s) red[t] += red[t + s];
        __syncthreads();
    }
    float l0 = red[0] + blin2[0];
    __syncthreads();

    // logit 1
    red[t] = yv * Wlin2[FOUT + t];
    __syncthreads();
    for (int s = FOUT / 2; s > 0; s >>= 1) {
        if (t < s) red[t] += red[t + s];
        __syncthreads();
    }
    float l1 = red[0] + blin2[1];

    if (t == 0) {
        float m = fmaxf(l0, l1);
        float e0 = expf(l0 - m), e1 = expf(l1 - m);
        float inv = 1.0f / (e0 + e1);
        probs[(long long)node * 2 + 0] = e0 * inv;
        probs[(long long)node * 2 + 1] = e1 * inv;
    }
}

extern "C" void kernel_launch(void* const* d_in, const int* in_sizes, int n_in,
                              void* d_out, int out_size, void* d_ws, size_t ws_size,
                              hipStream_t stream) {
    const float* x     = (const float*)d_in[0];
    const int*   ei    = (const int*)d_in[1];
    const int*   src   = ei;        // edge_index[0]
    const int*   tgt   = ei + NE;   // edge_index[1]
    const float* W1l   = (const float*)d_in[2];
    const float* b1l   = (const float*)d_in[3];
    const float* W1r   = (const float*)d_in[4];
    const float* Wlin  = (const float*)d_in[5];
    const float* blin  = (const float*)d_in[6];
    const float* W2l   = (const float*)d_in[7];
    const float* b2l   = (const float*)d_in[8];
    const float* W2r   = (const float*)d_in[9];
    const float* Wlin2 = (const float*)d_in[10];
    const float* blin2 = (const float*)d_in[11];

    float* probs = (float*)d_out;              // [N,2]
    float* y     = (float*)d_out + 2 * NN;     // [N,128]

    float* deg  = (float*)d_ws;                          // N
    float* bufA = deg + NN;                              // N*128 (agg1, later hr)
    float* bufB = bufA + (size_t)NN * FIN;               // N*256 (h, later agg2)

    // zero deg + agg1 (contiguous)
    hipMemsetAsync(deg, 0, sizeof(float) * (NN + (size_t)NN * FIN), stream);

    deg_kernel<<<(NE + 255) / 256, 256, 0, stream>>>(tgt, deg);

    // conv1 aggregation: agg1 = segment_sum(x[src], tgt)
    {
        long long total = (long long)NE * 32;
        int blocks = (int)((total + 255) / 256);
        scatter128<<<blocks, 256, 0, stream>>>(x, src, tgt, bufA);
    }

    // conv1: h = l2norm(mean@W1l.T + b1l + x@W1r.T)   -> bufB [N,256]
    conv1_kernel<<<NN, 256, 0, stream>>>(bufA, deg, x, W1l, b1l, W1r, bufB);

    // hr = relu(h@Wlin.T + blin)   -> bufA [N,128] (agg1 dead)
    linrelu_kernel<<<NN, 128, 0, stream>>>(bufB, Wlin, blin, bufA);

    // conv2 aggregation: agg2 = segment_sum(hr[src], tgt) -> bufB (reuse, h dead)
    hipMemsetAsync(bufB, 0, sizeof(float) * (size_t)NN * FOUT, stream);
    {
        long long total = (long long)NE * 32;
        int blocks = (int)((total + 255) / 256);
        scatter128<<<blocks, 256, 0, stream>>>(bufA, src, tgt, bufB);
    }

    // conv2 + linear2 + softmax
    conv2_kernel<<<NN, 128, 0, stream>>>(bufB, deg, bufA, W2l, b2l, W2r,
                                         Wlin2, blin2, probs, y);
}

// Round 2
// 11497.115 us; speedup vs baseline: 1.0399x; 1.0399x over previous
//
#include <hip/hip_runtime.h>
#include <hip/hip_bf16.h>

#define NN   100000
#define NE   1600000

typedef __attribute__((ext_vector_type(8))) short short8;
typedef __attribute__((ext_vector_type(4))) float f32x4;

__device__ __forceinline__ ushort f2bf(float f) {
    union { float f; uint u; } v; v.f = f;
    uint u = v.u;
    return (ushort)((u + 0x7FFFu + ((u >> 16) & 1u)) >> 16);
}
__device__ __forceinline__ float bf2f(uint b) {
    union { uint u; float f; } v; v.u = b << 16;
    return v.f;
}
// XOR-swizzle for 512B-stride LDS rows (guide G4): spread 16 rows over 8 16B slots
__device__ __forceinline__ int swz(int off) { return off ^ (((off >> 9) & 7) << 4); }

// ---------------- degree ----------------
__global__ __launch_bounds__(256) void deg_kernel(const int* __restrict__ tgt,
                                                  float* __restrict__ deg) {
    int e = blockIdx.x * blockDim.x + threadIdx.x;
    if (e < NE) atomicAdd(&deg[tgt[e]], 1.0f);
}

// ---------------- weight prep: fp32 -> bf16, concat [Wl|Wr] ----------------
__global__ __launch_bounds__(256) void prep_w(const float* __restrict__ W1l,
                                              const float* __restrict__ W1r,
                                              const float* __restrict__ Wlin,
                                              const float* __restrict__ W2l,
                                              const float* __restrict__ W2r,
                                              ushort* __restrict__ Wcat1,
                                              ushort* __restrict__ Wlinb,
                                              ushort* __restrict__ Wcat2) {
    int i = blockIdx.x * 256 + threadIdx.x;
    if (i < 65536) {               // Wcat1 [256][256]
        int o = i >> 8, k = i & 255;
        float v = (k < 128) ? W1l[o * 128 + k] : W1r[o * 128 + k - 128];
        Wcat1[i] = f2bf(v);
    } else if (i < 98304) {        // Wlin [128][256]
        int j = i - 65536;
        Wlinb[j] = f2bf(Wlin[j]);
    } else {                       // Wcat2 [128][256]
        int j = i - 98304;
        int o = j >> 8, k = j & 255;
        float v = (k < 128) ? W2l[o * 128 + k] : W2r[o * 128 + k - 128];
        Wcat2[j] = f2bf(v);
    }
}

// ---------------- x fp32 -> bf16 ----------------
__global__ __launch_bounds__(256) void xcvt(const float* __restrict__ x,
                                            ushort* __restrict__ xbf) {
    int i = blockIdx.x * 256 + threadIdx.x;   // 3.2M threads, 4 elems each
    float4 v = ((const float4*)x)[i];
    ushort4 p;
    p.x = f2bf(v.x); p.y = f2bf(v.y); p.z = f2bf(v.z); p.w = f2bf(v.w);
    ((ushort4*)xbf)[i] = p;
}

// ---------------- scatter-add of bf16 rows into fp32 agg ----------------
// 16 threads per edge, 8 cols each: 16B coalesced gather + 8 fp32 atomics
__global__ __launch_bounds__(256) void scatter_bf(const ushort* __restrict__ xin,
                                                  const int* __restrict__ src,
                                                  const int* __restrict__ tgt,
                                                  float* __restrict__ agg) {
    uint idx = blockIdx.x * 256u + threadIdx.x;     // exactly NE*16 = 25.6M
    uint e = idx >> 4, c = (idx & 15u) << 3;
    int s = src[e], t = tgt[e];
    uint4 raw = *(const uint4*)&xin[(size_t)s * 128 + c];
    float* a = &agg[(size_t)t * 128 + c];
    atomicAdd(a + 0, bf2f(raw.x & 0xffffu)); atomicAdd(a + 1, bf2f(raw.x >> 16));
    atomicAdd(a + 2, bf2f(raw.y & 0xffffu)); atomicAdd(a + 3, bf2f(raw.y >> 16));
    atomicAdd(a + 4, bf2f(raw.z & 0xffffu)); atomicAdd(a + 5, bf2f(raw.z >> 16));
    atomicAdd(a + 6, bf2f(raw.w & 0xffffu)); atomicAdd(a + 7, bf2f(raw.w >> 16));
}

// ---------------- conv1: h = l2norm([mean|x] @ Wcat1^T + b1l), bf16 out ------
// 64 nodes/block, 4 waves x 16 nodes; MFMA 16x16x32 bf16; N=256 (16 ntiles)
__global__ __launch_bounds__(256) void conv1_mfma(const float* __restrict__ agg,
                                                  const float* __restrict__ deg,
                                                  const ushort* __restrict__ xbf,
                                                  const ushort* __restrict__ Wcat,
                                                  const float* __restrict__ bias,
                                                  ushort* __restrict__ h) {
    __shared__ char As[64 * 512];
    __shared__ float invd[64];
    int m0 = blockIdx.x * 64;
    int tid = threadIdx.x;
    if (tid < 64) invd[tid] = 1.0f / fmaxf(deg[min(m0 + tid, NN - 1)], 1.0f);
    __syncthreads();
    // stage mean (cols 0-127): fp32 agg * invd -> bf16
    for (int c = tid; c < 2048; c += 256) {
        int m = c >> 5, kc = c & 31;
        int mm = min(m0 + m, NN - 1);
        float4 v = *(const float4*)&agg[(size_t)mm * 128 + kc * 4];
        float id = invd[m];
        ushort4 p;
        p.x = f2bf(v.x * id); p.y = f2bf(v.y * id);
        p.z = f2bf(v.z * id); p.w = f2bf(v.w * id);
        *(ushort4*)(As + swz(m * 512 + kc * 8)) = p;
    }
    // stage x (cols 128-255): bf16 16B chunks
    for (int c = tid; c < 1024; c += 256) {
        int m = c >> 4, kc = c & 15;
        int mm = min(m0 + m, NN - 1);
        *(uint4*)(As + swz(m * 512 + 256 + kc * 16)) =
            *(const uint4*)&xbf[(size_t)mm * 128 + kc * 8];
    }
    __syncthreads();

    int lane = tid & 63, wave = tid >> 6;
    int col = lane & 15, kg = lane >> 4;
    int mym = wave * 16 + col;
    short8 a[8];
#pragma unroll
    for (int ks = 0; ks < 8; ++ks)
        a[ks] = *(const short8*)(As + swz(mym * 512 + (ks * 32 + kg * 8) * 2));
    f32x4 acc[16];
#pragma unroll
    for (int nt = 0; nt < 16; ++nt) {
        f32x4 c = {0.f, 0.f, 0.f, 0.f};
        const ushort* wb = Wcat + (size_t)(nt * 16 + col) * 256 + kg * 8;
#pragma unroll
        for (int ks = 0; ks < 8; ++ks)
            c = __builtin_amdgcn_mfma_f32_16x16x32_bf16(a[ks], *(const short8*)(wb + ks * 32), c, 0, 0, 0);
        acc[nt] = c;
    }
    // epilogue: + bias, l2-norm over 256 cols; D layout: col=lane&15, row=kg*4+r
    float ssq[4] = {0.f, 0.f, 0.f, 0.f};
#pragma unroll
    for (int nt = 0; nt < 16; ++nt) {
        float b = bias[nt * 16 + col];
#pragma unroll
        for (int r = 0; r < 4; ++r) {
            acc[nt][r] += b;
            ssq[r] += acc[nt][r] * acc[nt][r];
        }
    }
#pragma unroll
    for (int off = 1; off < 16; off <<= 1)
#pragma unroll
        for (int r = 0; r < 4; ++r) ssq[r] += __shfl_xor(ssq[r], off);
#pragma unroll
    for (int r = 0; r < 4; ++r) {
        int node = m0 + wave * 16 + kg * 4 + r;
        if (node < NN) {
            float rn = 1.0f / fmaxf(sqrtf(ssq[r]), 1e-12f);
#pragma unroll
            for (int nt = 0; nt < 16; ++nt)
                h[(size_t)node * 256 + nt * 16 + col] = f2bf(acc[nt][r] * rn);
        }
    }
}

// ---------------- linear+relu: hr = relu(h @ Wlin^T + blin), bf16 ----------
__global__ __launch_bounds__(256) void lin_mfma(const ushort* __restrict__ h,
                                                const ushort* __restrict__ W,
                                                const float* __restrict__ bias,
                                                ushort* __restrict__ hr) {
    __shared__ char As[64 * 512];
    int m0 = blockIdx.x * 64;
    int tid = threadIdx.x;
    for (int c = tid; c < 2048; c += 256) {
        int m = c >> 5, kc = c & 31;
        int mm = min(m0 + m, NN - 1);
        *(uint4*)(As + swz(m * 512 + kc * 16)) =
            *(const uint4*)&h[(size_t)mm * 256 + kc * 8];
    }
    __syncthreads();
    int lane = tid & 63, wave = tid >> 6;
    int col = lane & 15, kg = lane >> 4;
    int mym = wave * 16 + col;
    short8 a[8];
#pragma unroll
    for (int ks = 0; ks < 8; ++ks)
        a[ks] = *(const short8*)(As + swz(mym * 512 + (ks * 32 + kg * 8) * 2));
    f32x4 acc[8];
#pragma unroll
    for (int nt = 0; nt < 8; ++nt) {
        f32x4 c = {0.f, 0.f, 0.f, 0.f};
        const ushort* wb = W + (size_t)(nt * 16 + col) * 256 + kg * 8;
#pragma unroll
        for (int ks = 0; ks < 8; ++ks)
            c = __builtin_amdgcn_mfma_f32_16x16x32_bf16(a[ks], *(const short8*)(wb + ks * 32), c, 0, 0, 0);
        acc[nt] = c;
    }
#pragma unroll
    for (int r = 0; r < 4; ++r) {
        int node = m0 + wave * 16 + kg * 4 + r;
        if (node < NN) {
#pragma unroll
            for (int nt = 0; nt < 8; ++nt) {
                float v = acc[nt][r] + bias[nt * 16 + col];
                hr[(size_t)node * 128 + nt * 16 + col] = f2bf(fmaxf(v, 0.f));
            }
        }
    }
}

// ------- conv2 + linear2 + softmax: y = l2norm([mean2|hr]@Wcat2^T + b2l) -----
__global__ __launch_bounds__(256) void conv2_mfma(const float* __restrict__ agg,
                                                  const float* __restrict__ deg,
                                                  const ushort* __restrict__ hr,
                                                  const ushort* __restrict__ Wcat,
                                                  const float* __restrict__ bias,
                                                  const float* __restrict__ Wlin2,
                                                  const float* __restrict__ blin2,
                                                  float* __restrict__ probs,
                                                  float* __restrict__ yout) {
    __shared__ char As[64 * 512];
    __shared__ float invd[64];
    int m0 = blockIdx.x * 64;
    int tid = threadIdx.x;
    if (tid < 64) invd[tid] = 1.0f / fmaxf(deg[min(m0 + tid, NN - 1)], 1.0f);
    __syncthreads();
    for (int c = tid; c < 2048; c += 256) {
        int m = c >> 5, kc = c & 31;
        int mm = min(m0 + m, NN - 1);
        float4 v = *(const float4*)&agg[(size_t)mm * 128 + kc * 4];
        float id = invd[m];
        ushort4 p;
        p.x = f2bf(v.x * id); p.y = f2bf(v.y * id);
        p.z = f2bf(v.z * id); p.w = f2bf(v.w * id);
        *(ushort4*)(As + swz(m * 512 + kc * 8)) = p;
    }
    for (int c = tid; c < 1024; c += 256) {
        int m = c >> 4, kc = c & 15;
        int mm = min(m0 + m, NN - 1);
        *(uint4*)(As + swz(m * 512 + 256 + kc * 16)) =
            *(const uint4*)&hr[(size_t)mm * 128 + kc * 8];
    }
    __syncthreads();

    int lane = tid & 63, wave = tid >> 6;
    int col = lane & 15, kg = lane >> 4;
    int mym = wave * 16 + col;
    short8 a[8];
#pragma unroll
    for (int ks = 0; ks < 8; ++ks)
        a[ks] = *(const short8*)(As + swz(mym * 512 + (ks * 32 + kg * 8) * 2));
    f32x4 acc[8];
#pragma unroll
    for (int nt = 0; nt < 8; ++nt) {
        f32x4 c = {0.f, 0.f, 0.f, 0.f};
        const ushort* wb = Wcat + (size_t)(nt * 16 + col) * 256 + kg * 8;
#pragma unroll
        for (int ks = 0; ks < 8; ++ks)
            c = __builtin_amdgcn_mfma_f32_16x16x32_bf16(a[ks], *(const short8*)(wb + ks * 32), c, 0, 0, 0);
        acc[nt] = c;
    }
    float ssq[4] = {0.f, 0.f, 0.f, 0.f};
#pragma unroll
    for (int nt = 0; nt < 8; ++nt) {
        float b = bias[nt * 16 + col];
#pragma unroll
        for (int r = 0; r < 4; ++r) {
            acc[nt][r] += b;
            ssq[r] += acc[nt][r] * acc[nt][r];
        }
    }
#pragma unroll
    for (int off = 1; off < 16; off <<= 1)
#pragma unroll
        for (int r = 0; r < 4; ++r) ssq[r] += __shfl_xor(ssq[r], off);
    float rn[4], p0[4] = {0.f,0.f,0.f,0.f}, p1[4] = {0.f,0.f,0.f,0.f};
#pragma unroll
    for (int r = 0; r < 4; ++r) rn[r] = 1.0f / fmaxf(sqrtf(ssq[r]), 1e-12f);
#pragma unroll
    for (int nt = 0; nt < 8; ++nt) {
        float w0 = Wlin2[nt * 16 + col], w1 = Wlin2[128 + nt * 16 + col];
#pragma unroll
        for (int r = 0; r < 4; ++r) {
            float yv = acc[nt][r] * rn[r];
            acc[nt][r] = yv;
            p0[r] += yv * w0;
            p1[r] += yv * w1;
        }
    }
#pragma unroll
    for (int off = 1; off < 16; off <<= 1)
#pragma unroll
        for (int r = 0; r < 4; ++r) { p0[r] += __shfl_xor(p0[r], off); p1[r] += __shfl_xor(p1[r], off); }
#pragma unroll
    for (int r = 0; r < 4; ++r) {
        int node = m0 + wave * 16 + kg * 4 + r;
        if (node < NN) {
#pragma unroll
            for (int nt = 0; nt < 8; ++nt)
                yout[(size_t)node * 128 + nt * 16 + col] = acc[nt][r];
            if (col == 0) {
                float l0 = p0[r] + blin2[0], l1 = p1[r] + blin2[1];
                float mx = fmaxf(l0, l1);
                float e0 = expf(l0 - mx), e1 = expf(l1 - mx);
                float inv = 1.0f / (e0 + e1);
                probs[(size_t)node * 2 + 0] = e0 * inv;
                probs[(size_t)node * 2 + 1] = e1 * inv;
            }
        }
    }
}

extern "C" void kernel_launch(void* const* d_in, const int* in_sizes, int n_in,
                              void* d_out, int out_size, void* d_ws, size_t ws_size,
                              hipStream_t stream) {
    const float* x     = (const float*)d_in[0];
    const int*   ei    = (const int*)d_in[1];
    const int*   src   = ei;
    const int*   tgt   = ei + NE;
    const float* W1l   = (const float*)d_in[2];
    const float* b1l   = (const float*)d_in[3];
    const float* W1r   = (const float*)d_in[4];
    const float* Wlin  = (const float*)d_in[5];
    const float* blin  = (const float*)d_in[6];
    const float* W2l   = (const float*)d_in[7];
    const float* b2l   = (const float*)d_in[8];
    const float* W2r   = (const float*)d_in[9];
    const float* Wlin2 = (const float*)d_in[10];
    const float* blin2 = (const float*)d_in[11];

    float* probs = (float*)d_out;              // [N,2]
    float* y     = (float*)d_out + 2 * NN;     // [N,128]

    // ws layout
    float*  agg   = (float*)d_ws;                       // N*128 f32 (agg1, then agg2)
    float*  deg   = agg + (size_t)NN * 128;             // N f32
    ushort* Wcat1 = (ushort*)(deg + NN);                // 256*256 bf16
    ushort* Wlinb = Wcat1 + 65536;                      // 128*256 bf16
    ushort* Wcat2 = Wlinb + 32768;                      // 128*256 bf16
    ushort* xbf   = Wcat2 + 32768;                      // N*128 bf16 (later hr)
    ushort* h     = xbf + (size_t)NN * 128;             // N*256 bf16
    ushort* hr    = xbf;                                // reuse after conv1

    // zero agg + deg (contiguous)
    hipMemsetAsync(agg, 0, sizeof(float) * ((size_t)NN * 128 + NN), stream);

    prep_w<<<512, 256, 0, stream>>>(W1l, W1r, Wlin, W2l, W2r, Wcat1, Wlinb, Wcat2);
    xcvt<<<NN * 32 / 256, 256, 0, stream>>>(x, xbf);
    deg_kernel<<<(NE + 255) / 256, 256, 0, stream>>>(tgt, deg);

    scatter_bf<<<NE * 16 / 256, 256, 0, stream>>>(xbf, src, tgt, agg);
    conv1_mfma<<<(NN + 63) / 64, 256, 0, stream>>>(agg, deg, xbf, Wcat1, b1l, h);
    lin_mfma<<<(NN + 63) / 64, 256, 0, stream>>>(h, Wlinb, blin, hr);

    hipMemsetAsync(agg, 0, sizeof(float) * (size_t)NN * 128, stream);
    scatter_bf<<<NE * 16 / 256, 256, 0, stream>>>(hr, src, tgt, agg);
    conv2_mfma<<<(NN + 63) / 64, 256, 0, stream>>>(agg, deg, hr, Wcat2, b2l,
                                                   Wlin2, blin2, probs, y);
}

// Round 3
// 869.523 us; speedup vs baseline: 13.7504x; 13.2223x over previous
//
#include <hip/hip_runtime.h>
#include <hip/hip_bf16.h>

#define NN   100000
#define NE   1600000

typedef __attribute__((ext_vector_type(8))) short short8;
typedef __attribute__((ext_vector_type(4))) float f32x4;

__device__ __forceinline__ ushort f2bf(float f) {
    union { float f; uint u; } v; v.f = f;
    uint u = v.u;
    return (ushort)((u + 0x7FFFu + ((u >> 16) & 1u)) >> 16);
}
__device__ __forceinline__ float bf2f(uint b) {
    union { uint u; float f; } v; v.u = b << 16;
    return v.f;
}
// XOR-swizzle for 512B-stride LDS rows (guide G4)
__device__ __forceinline__ int swz(int off) { return off ^ (((off >> 9) & 7) << 4); }

// ---------------- CSR build ----------------
__global__ __launch_bounds__(256) void hist_kernel(const int* __restrict__ tgt,
                                                   int* __restrict__ degi) {
    int e = blockIdx.x * 256 + threadIdx.x;
    if (e < NE) atomicAdd(&degi[tgt[e]], 1);
}

// single-block exclusive scan of degi[0..NN) -> rowstart[0..NN], cursor copy
__global__ __launch_bounds__(1024) void scan_kernel(const int* __restrict__ degi,
                                                    int* __restrict__ rowstart,
                                                    int* __restrict__ cursor) {
    __shared__ int wsum[16];
    const int CH = (NN + 1023) / 1024;   // 98
    int t = threadIdx.x;
    int beg = t * CH, end = min(beg + CH, NN);
    int sum = 0;
    for (int i = beg; i < end; ++i) sum += degi[i];
    int lane = t & 63, wid = t >> 6;
    int inc = sum;
#pragma unroll
    for (int off = 1; off < 64; off <<= 1) {
        int v = __shfl_up(inc, off);
        if (lane >= off) inc += v;
    }
    if (lane == 63) wsum[wid] = inc;
    __syncthreads();
    if (wid == 0) {
        int v = (lane < 16) ? wsum[lane] : 0;
#pragma unroll
        for (int off = 1; off < 16; off <<= 1) {
            int u = __shfl_up(v, off);
            if (lane >= off) v += u;
        }
        if (lane < 16) wsum[lane] = v;
    }
    __syncthreads();
    int waveoff = (wid > 0) ? wsum[wid - 1] : 0;
    int run = waveoff + inc - sum;       // exclusive prefix of this chunk
    for (int i = beg; i < end; ++i) {
        rowstart[i] = run; cursor[i] = run;
        run += degi[i];
    }
    if (t == 1023) rowstart[NN] = run;   // == NE
}

__global__ __launch_bounds__(256) void fill_kernel(const int* __restrict__ src,
                                                   const int* __restrict__ tgt,
                                                   int* __restrict__ cursor,
                                                   int* __restrict__ sortedSrc) {
    int e = blockIdx.x * 256 + threadIdx.x;
    if (e < NE) {
        int pos = atomicAdd(&cursor[tgt[e]], 1);
        sortedSrc[pos] = src[e];
    }
}

// ---------------- gather mean: one wave per node, 2 bf16 cols per lane ------
__global__ __launch_bounds__(256) void gather_mean(const ushort* __restrict__ xin,
                                                   const int* __restrict__ rowstart,
                                                   const int* __restrict__ sortedSrc,
                                                   ushort* __restrict__ mean) {
    int node = blockIdx.x * 4 + (threadIdx.x >> 6);
    if (node >= NN) return;
    int lane = threadIdx.x & 63;
    int beg = rowstart[node], end = rowstart[node + 1];
    float a0 = 0.f, a1 = 0.f, b0 = 0.f, b1 = 0.f;
    int i = beg;
    for (; i + 1 < end; i += 2) {
        int s0 = sortedSrc[i], s1 = sortedSrc[i + 1];
        uint v0 = *(const uint*)&xin[(size_t)s0 * 128 + lane * 2];
        uint v1 = *(const uint*)&xin[(size_t)s1 * 128 + lane * 2];
        a0 += bf2f(v0 & 0xffffu); a1 += bf2f(v0 >> 16);
        b0 += bf2f(v1 & 0xffffu); b1 += bf2f(v1 >> 16);
    }
    if (i < end) {
        int s0 = sortedSrc[i];
        uint v0 = *(const uint*)&xin[(size_t)s0 * 128 + lane * 2];
        a0 += bf2f(v0 & 0xffffu); a1 += bf2f(v0 >> 16);
    }
    a0 += b0; a1 += b1;
    float id = 1.0f / fmaxf((float)(end - beg), 1.0f);
    ushort2 p; p.x = f2bf(a0 * id); p.y = f2bf(a1 * id);
    *(ushort2*)&mean[(size_t)node * 128 + lane * 2] = p;
}

// ---------------- weight prep: fp32 -> bf16, concat [Wl|Wr] ----------------
__global__ __launch_bounds__(256) void prep_w(const float* __restrict__ W1l,
                                              const float* __restrict__ W1r,
                                              const float* __restrict__ Wlin,
                                              const float* __restrict__ W2l,
                                              const float* __restrict__ W2r,
                                              ushort* __restrict__ Wcat1,
                                              ushort* __restrict__ Wlinb,
                                              ushort* __restrict__ Wcat2) {
    int i = blockIdx.x * 256 + threadIdx.x;
    if (i < 65536) {               // Wcat1 [256][256]
        int o = i >> 8, k = i & 255;
        float v = (k < 128) ? W1l[o * 128 + k] : W1r[o * 128 + k - 128];
        Wcat1[i] = f2bf(v);
    } else if (i < 98304) {        // Wlin [128][256]
        int j = i - 65536;
        Wlinb[j] = f2bf(Wlin[j]);
    } else {                       // Wcat2 [128][256]
        int j = i - 98304;
        int o = j >> 8, k = j & 255;
        float v = (k < 128) ? W2l[o * 128 + k] : W2r[o * 128 + k - 128];
        Wcat2[j] = f2bf(v);
    }
}

// ---------------- x fp32 -> bf16 ----------------
__global__ __launch_bounds__(256) void xcvt(const float* __restrict__ x,
                                            ushort* __restrict__ xbf) {
    int i = blockIdx.x * 256 + threadIdx.x;
    float4 v = ((const float4*)x)[i];
    ushort4 p;
    p.x = f2bf(v.x); p.y = f2bf(v.y); p.z = f2bf(v.z); p.w = f2bf(v.w);
    ((ushort4*)xbf)[i] = p;
}

// ---------------- conv1: h = l2norm([mean|x] @ Wcat1^T + b1l), bf16 out ------
__global__ __launch_bounds__(256) void conv1_mfma(const ushort* __restrict__ mean,
                                                  const ushort* __restrict__ xbf,
                                                  const ushort* __restrict__ Wcat,
                                                  const float* __restrict__ bias,
                                                  ushort* __restrict__ h) {
    __shared__ char As[64 * 512];
    int m0 = blockIdx.x * 64;
    int tid = threadIdx.x;
    for (int c = tid; c < 2048; c += 256) {
        int m = c >> 5, kc = c & 31;
        int mm = min(m0 + m, NN - 1);
        uint4 v = (kc < 16) ? *(const uint4*)&mean[(size_t)mm * 128 + kc * 8]
                            : *(const uint4*)&xbf[(size_t)mm * 128 + (kc - 16) * 8];
        *(uint4*)(As + swz(m * 512 + kc * 16)) = v;
    }
    __syncthreads();

    int lane = tid & 63, wave = tid >> 6;
    int col = lane & 15, kg = lane >> 4;
    int mym = wave * 16 + col;
    short8 a[8];
#pragma unroll
    for (int ks = 0; ks < 8; ++ks)
        a[ks] = *(const short8*)(As + swz(mym * 512 + (ks * 32 + kg * 8) * 2));
    f32x4 acc[16];
#pragma unroll
    for (int nt = 0; nt < 16; ++nt) {
        f32x4 c = {0.f, 0.f, 0.f, 0.f};
        const ushort* wb = Wcat + (size_t)(nt * 16 + col) * 256 + kg * 8;
#pragma unroll
        for (int ks = 0; ks < 8; ++ks)
            c = __builtin_amdgcn_mfma_f32_16x16x32_bf16(a[ks], *(const short8*)(wb + ks * 32), c, 0, 0, 0);
        acc[nt] = c;
    }
    float ssq[4] = {0.f, 0.f, 0.f, 0.f};
#pragma unroll
    for (int nt = 0; nt < 16; ++nt) {
        float b = bias[nt * 16 + col];
#pragma unroll
        for (int r = 0; r < 4; ++r) {
            acc[nt][r] += b;
            ssq[r] += acc[nt][r] * acc[nt][r];
        }
    }
#pragma unroll
    for (int off = 1; off < 16; off <<= 1)
#pragma unroll
        for (int r = 0; r < 4; ++r) ssq[r] += __shfl_xor(ssq[r], off);
#pragma unroll
    for (int r = 0; r < 4; ++r) {
        int node = m0 + wave * 16 + kg * 4 + r;
        if (node < NN) {
            float rn = 1.0f / fmaxf(sqrtf(ssq[r]), 1e-12f);
#pragma unroll
            for (int nt = 0; nt < 16; ++nt)
                h[(size_t)node * 256 + nt * 16 + col] = f2bf(acc[nt][r] * rn);
        }
    }
}

// ---------------- linear+relu: hr = relu(h @ Wlin^T + blin), bf16 ----------
__global__ __launch_bounds__(256) void lin_mfma(const ushort* __restrict__ h,
                                                const ushort* __restrict__ W,
                                                const float* __restrict__ bias,
                                                ushort* __restrict__ hr) {
    __shared__ char As[64 * 512];
    int m0 = blockIdx.x * 64;
    int tid = threadIdx.x;
    for (int c = tid; c < 2048; c += 256) {
        int m = c >> 5, kc = c & 31;
        int mm = min(m0 + m, NN - 1);
        *(uint4*)(As + swz(m * 512 + kc * 16)) =
            *(const uint4*)&h[(size_t)mm * 256 + kc * 8];
    }
    __syncthreads();
    int lane = tid & 63, wave = tid >> 6;
    int col = lane & 15, kg = lane >> 4;
    int mym = wave * 16 + col;
    short8 a[8];
#pragma unroll
    for (int ks = 0; ks < 8; ++ks)
        a[ks] = *(const short8*)(As + swz(mym * 512 + (ks * 32 + kg * 8) * 2));
    f32x4 acc[8];
#pragma unroll
    for (int nt = 0; nt < 8; ++nt) {
        f32x4 c = {0.f, 0.f, 0.f, 0.f};
        const ushort* wb = W + (size_t)(nt * 16 + col) * 256 + kg * 8;
#pragma unroll
        for (int ks = 0; ks < 8; ++ks)
            c = __builtin_amdgcn_mfma_f32_16x16x32_bf16(a[ks], *(const short8*)(wb + ks * 32), c, 0, 0, 0);
        acc[nt] = c;
    }
#pragma unroll
    for (int r = 0; r < 4; ++r) {
        int node = m0 + wave * 16 + kg * 4 + r;
        if (node < NN) {
#pragma unroll
            for (int nt = 0; nt < 8; ++nt) {
                float v = acc[nt][r] + bias[nt * 16 + col];
                hr[(size_t)node * 128 + nt * 16 + col] = f2bf(fmaxf(v, 0.f));
            }
        }
    }
}

// ------- conv2 + linear2 + softmax: y = l2norm([mean2|hr]@Wcat2^T + b2l) -----
__global__ __launch_bounds__(256) void conv2_mfma(const ushort* __restrict__ mean,
                                                  const ushort* __restrict__ hr,
                                                  const ushort* __restrict__ Wcat,
                                                  const float* __restrict__ bias,
                                                  const float* __restrict__ Wlin2,
                                                  const float* __restrict__ blin2,
                                                  float* __restrict__ probs,
                                                  float* __restrict__ yout) {
    __shared__ char As[64 * 512];
    int m0 = blockIdx.x * 64;
    int tid = threadIdx.x;
    for (int c = tid; c < 2048; c += 256) {
        int m = c >> 5, kc = c & 31;
        int mm = min(m0 + m, NN - 1);
        uint4 v = (kc < 16) ? *(const uint4*)&mean[(size_t)mm * 128 + kc * 8]
                            : *(const uint4*)&hr[(size_t)mm * 128 + (kc - 16) * 8];
        *(uint4*)(As + swz(m * 512 + kc * 16)) = v;
    }
    __syncthreads();

    int lane = tid & 63, wave = tid >> 6;
    int col = lane & 15, kg = lane >> 4;
    int mym = wave * 16 + col;
    short8 a[8];
#pragma unroll
    for (int ks = 0; ks < 8; ++ks)
        a[ks] = *(const short8*)(As + swz(mym * 512 + (ks * 32 + kg * 8) * 2));
    f32x4 acc[8];
#pragma unroll
    for (int nt = 0; nt < 8; ++nt) {
        f32x4 c = {0.f, 0.f, 0.f, 0.f};
        const ushort* wb = Wcat + (size_t)(nt * 16 + col) * 256 + kg * 8;
#pragma unroll
        for (int ks = 0; ks < 8; ++ks)
            c = __builtin_amdgcn_mfma_f32_16x16x32_bf16(a[ks], *(const short8*)(wb + ks * 32), c, 0, 0, 0);
        acc[nt] = c;
    }
    float ssq[4] = {0.f, 0.f, 0.f, 0.f};
#pragma unroll
    for (int nt = 0; nt < 8; ++nt) {
        float b = bias[nt * 16 + col];
#pragma unroll
        for (int r = 0; r < 4; ++r) {
            acc[nt][r] += b;
            ssq[r] += acc[nt][r] * acc[nt][r];
        }
    }
#pragma unroll
    for (int off = 1; off < 16; off <<= 1)
#pragma unroll
        for (int r = 0; r < 4; ++r) ssq[r] += __shfl_xor(ssq[r], off);
    float rn[4], p0[4] = {0.f,0.f,0.f,0.f}, p1[4] = {0.f,0.f,0.f,0.f};
#pragma unroll
    for (int r = 0; r < 4; ++r) rn[r] = 1.0f / fmaxf(sqrtf(ssq[r]), 1e-12f);
#pragma unroll
    for (int nt = 0; nt < 8; ++nt) {
        float w0 = Wlin2[nt * 16 + col], w1 = Wlin2[128 + nt * 16 + col];
#pragma unroll
        for (int r = 0; r < 4; ++r) {
            float yv = acc[nt][r] * rn[r];
            acc[nt][r] = yv;
            p0[r] += yv * w0;
            p1[r] += yv * w1;
        }
    }
#pragma unroll
    for (int off = 1; off < 16; off <<= 1)
#pragma unroll
        for (int r = 0; r < 4; ++r) { p0[r] += __shfl_xor(p0[r], off); p1[r] += __shfl_xor(p1[r], off); }
#pragma unroll
    for (int r = 0; r < 4; ++r) {
        int node = m0 + wave * 16 + kg * 4 + r;
        if (node < NN) {
#pragma unroll
            for (int nt = 0; nt < 8; ++nt)
                yout[(size_t)node * 128 + nt * 16 + col] = acc[nt][r];
            if (col == 0) {
                float l0 = p0[r] + blin2[0], l1 = p1[r] + blin2[1];
                float mx = fmaxf(l0, l1);
                float e0 = expf(l0 - mx), e1 = expf(l1 - mx);
                float inv = 1.0f / (e0 + e1);
                probs[(size_t)node * 2 + 0] = e0 * inv;
                probs[(size_t)node * 2 + 1] = e1 * inv;
            }
        }
    }
}

extern "C" void kernel_launch(void* const* d_in, const int* in_sizes, int n_in,
                              void* d_out, int out_size, void* d_ws, size_t ws_size,
                              hipStream_t stream) {
    const float* x     = (const float*)d_in[0];
    const int*   ei    = (const int*)d_in[1];
    const int*   src   = ei;
    const int*   tgt   = ei + NE;
    const float* W1l   = (const float*)d_in[2];
    const float* b1l   = (const float*)d_in[3];
    const float* W1r   = (const float*)d_in[4];
    const float* Wlin  = (const float*)d_in[5];
    const float* blin  = (const float*)d_in[6];
    const float* W2l   = (const float*)d_in[7];
    const float* b2l   = (const float*)d_in[8];
    const float* W2r   = (const float*)d_in[9];
    const float* Wlin2 = (const float*)d_in[10];
    const float* blin2 = (const float*)d_in[11];

    float* probs = (float*)d_out;              // [N,2]
    float* y     = (float*)d_out + 2 * NN;     // [N,128]

    // ws layout
    int*    degi      = (int*)d_ws;                     // N
    int*    rowstart  = degi + NN;                      // N+1
    int*    cursor    = rowstart + NN + 1;              // N
    int*    sortedSrc = cursor + NN;                    // NE
    ushort* Wcat1     = (ushort*)(sortedSrc + NE);      // 256*256
    ushort* Wlinb     = Wcat1 + 65536;                  // 128*256
    ushort* Wcat2     = Wlinb + 32768;                  // 128*256
    ushort* xbf       = Wcat2 + 32768;                  // N*128 (later hr)
    ushort* h         = xbf + (size_t)NN * 128;         // N*256
    ushort* mean      = h + (size_t)NN * 256;           // N*128 (mean1 then mean2)
    ushort* hr        = xbf;                            // reuse after conv1

    hipMemsetAsync(degi, 0, sizeof(int) * NN, stream);

    prep_w<<<512, 256, 0, stream>>>(W1l, W1r, Wlin, W2l, W2r, Wcat1, Wlinb, Wcat2);
    xcvt<<<NN * 32 / 256, 256, 0, stream>>>(x, xbf);

    hist_kernel<<<(NE + 255) / 256, 256, 0, stream>>>(tgt, degi);
    scan_kernel<<<1, 1024, 0, stream>>>(degi, rowstart, cursor);
    fill_kernel<<<(NE + 255) / 256, 256, 0, stream>>>(src, tgt, cursor, sortedSrc);

    gather_mean<<<(NN + 3) / 4, 256, 0, stream>>>(xbf, rowstart, sortedSrc, mean);
    conv1_mfma<<<(NN + 63) / 64, 256, 0, stream>>>(mean, xbf, Wcat1, b1l, h);
    lin_mfma<<<(NN + 63) / 64, 256, 0, stream>>>(h, Wlinb, blin, hr);

    gather_mean<<<(NN + 3) / 4, 256, 0, stream>>>(hr, rowstart, sortedSrc, mean);
    conv2_mfma<<<(NN + 63) / 64, 256, 0, stream>>>(mean, hr, Wcat2, b2l,
                                                   Wlin2, blin2, probs, y);
}

// Round 4
// 651.270 us; speedup vs baseline: 18.3585x; 1.3351x over previous
//
#include <hip/hip_runtime.h>
#include <hip/hip_bf16.h>

#define NN   100000
#define NE   1600000

typedef __attribute__((ext_vector_type(8))) short short8;
typedef __attribute__((ext_vector_type(4))) float f32x4;

__device__ __forceinline__ ushort f2bf(float f) {
    union { float f; uint u; } v; v.f = f;
    uint u = v.u;
    return (ushort)((u + 0x7FFFu + ((u >> 16) & 1u)) >> 16);
}
__device__ __forceinline__ float bf2f(uint b) {
    union { uint u; float f; } v; v.u = b << 16;
    return v.f;
}
// XOR-swizzle for 512B-stride LDS rows (guide G4)
__device__ __forceinline__ int swz(int off) { return off ^ (((off >> 9) & 7) << 4); }

// ---------------- CSR build ----------------
__global__ __launch_bounds__(256) void hist_kernel(const int* __restrict__ tgt,
                                                   int* __restrict__ degi) {
    int e = blockIdx.x * 256 + threadIdx.x;
    if (e < NE) atomicAdd(&degi[tgt[e]], 1);
}

// phase 1: per-1024-node block sums
__global__ __launch_bounds__(256) void scan_reduce(const int* __restrict__ degi,
                                                   int* __restrict__ bsum) {
    int b = blockIdx.x, t = threadIdx.x;
    int i0 = b * 1024 + t * 4;
    int s = 0;
    if (i0 + 3 < NN) {
        int4 v = *(const int4*)&degi[i0];
        s = v.x + v.y + v.z + v.w;
    } else {
        for (int k = 0; k < 4; ++k) if (i0 + k < NN) s += degi[i0 + k];
    }
    int lane = t & 63, wid = t >> 6;
#pragma unroll
    for (int off = 32; off >= 1; off >>= 1) s += __shfl_xor(s, off);
    __shared__ int ws[4];
    if (lane == 0) ws[wid] = s;
    __syncthreads();
    if (t == 0) bsum[b] = ws[0] + ws[1] + ws[2] + ws[3];
}

// phase 2: exclusive scan of block sums (nb <= 128), single block
__global__ __launch_bounds__(128) void scan_bsum(int* __restrict__ bsum, int nb) {
    int t = threadIdx.x;
    int v = (t < nb) ? bsum[t] : 0;
    int lane = t & 63, wid = t >> 6;
    int inc = v;
#pragma unroll
    for (int off = 1; off < 64; off <<= 1) {
        int u = __shfl_up(inc, off);
        if (lane >= off) inc += u;
    }
    __shared__ int ws[2];
    if (lane == 63) ws[wid] = inc;
    __syncthreads();
    int add = (wid == 1) ? ws[0] : 0;
    if (t < nb) bsum[t] = inc - v + add;    // exclusive
}

// phase 3: per-block local scan + offset, write rowstart & cursor
__global__ __launch_bounds__(256) void scan_write(const int* __restrict__ degi,
                                                  const int* __restrict__ bsum,
                                                  int* __restrict__ rowstart,
                                                  int* __restrict__ cursor) {
    int b = blockIdx.x, t = threadIdx.x;
    int i0 = b * 1024 + t * 4;
    int d[4] = {0, 0, 0, 0};
    if (i0 + 3 < NN) {
        int4 v = *(const int4*)&degi[i0];
        d[0] = v.x; d[1] = v.y; d[2] = v.z; d[3] = v.w;
    } else {
        for (int k = 0; k < 4; ++k) if (i0 + k < NN) d[k] = degi[i0 + k];
    }
    int s = d[0] + d[1] + d[2] + d[3];
    int lane = t & 63, wid = t >> 6;
    int inc = s;
#pragma unroll
    for (int off = 1; off < 64; off <<= 1) {
        int u = __shfl_up(inc, off);
        if (lane >= off) inc += u;
    }
    __shared__ int ws[4];
    if (lane == 63) ws[wid] = inc;
    __syncthreads();
    int woff = 0;
    for (int w = 0; w < wid; ++w) woff += ws[w];
    int ex = inc - s + woff + bsum[b];
    for (int k = 0; k < 4; ++k) {
        int idx = i0 + k;
        if (idx < NN) {
            rowstart[idx] = ex; cursor[idx] = ex;
            ex += d[k];
            if (idx == NN - 1) rowstart[NN] = ex;
        }
    }
}

__global__ __launch_bounds__(256) void fill_kernel(const int* __restrict__ src,
                                                   const int* __restrict__ tgt,
                                                   int* __restrict__ cursor,
                                                   int* __restrict__ sortedSrc) {
    int e = blockIdx.x * 256 + threadIdx.x;
    if (e < NE) {
        int pos = atomicAdd(&cursor[tgt[e]], 1);
        sortedSrc[pos] = src[e];
    }
}

// ------- gather mean: one wave per node, half-wave per edge, 8B/lane --------
__global__ __launch_bounds__(256) void gather_mean(const ushort* __restrict__ xin,
                                                   const int* __restrict__ rowstart,
                                                   const int* __restrict__ sortedSrc,
                                                   ushort* __restrict__ mean) {
    int node = blockIdx.x * 4 + (threadIdx.x >> 6);
    if (node >= NN) return;
    int lane = threadIdx.x & 63;
    int half = lane >> 5, l = lane & 31;
    int beg = rowstart[node], end = rowstart[node + 1];
    float a0 = 0.f, a1 = 0.f, a2 = 0.f, a3 = 0.f;
    for (int i = beg + half; i < end; i += 2) {
        int s = sortedSrc[i];
        uint2 v = *(const uint2*)&xin[(size_t)s * 128 + l * 4];
        a0 += bf2f(v.x & 0xffffu); a1 += bf2f(v.x >> 16);
        a2 += bf2f(v.y & 0xffffu); a3 += bf2f(v.y >> 16);
    }
    a0 += __shfl_xor(a0, 32); a1 += __shfl_xor(a1, 32);
    a2 += __shfl_xor(a2, 32); a3 += __shfl_xor(a3, 32);
    if (half == 0) {
        float id = 1.0f / fmaxf((float)(end - beg), 1.0f);
        ushort4 p;
        p.x = f2bf(a0 * id); p.y = f2bf(a1 * id);
        p.z = f2bf(a2 * id); p.w = f2bf(a3 * id);
        *(ushort4*)&mean[(size_t)node * 128 + l * 4] = p;
    }
}

// ---------------- weight prep: fp32 -> bf16, concat [Wl|Wr] ----------------
__global__ __launch_bounds__(256) void prep_w(const float* __restrict__ W1l,
                                              const float* __restrict__ W1r,
                                              const float* __restrict__ Wlin,
                                              const float* __restrict__ W2l,
                                              const float* __restrict__ W2r,
                                              ushort* __restrict__ Wcat1,
                                              ushort* __restrict__ Wlinb,
                                              ushort* __restrict__ Wcat2) {
    int i = blockIdx.x * 256 + threadIdx.x;
    if (i < 65536) {               // Wcat1 [256][256]
        int o = i >> 8, k = i & 255;
        float v = (k < 128) ? W1l[o * 128 + k] : W1r[o * 128 + k - 128];
        Wcat1[i] = f2bf(v);
    } else if (i < 98304) {        // Wlin [128][256]
        int j = i - 65536;
        Wlinb[j] = f2bf(Wlin[j]);
    } else {                       // Wcat2 [128][256]
        int j = i - 98304;
        int o = j >> 8, k = j & 255;
        float v = (k < 128) ? W2l[o * 128 + k] : W2r[o * 128 + k - 128];
        Wcat2[j] = f2bf(v);
    }
}

// ---------------- x fp32 -> bf16 ----------------
__global__ __launch_bounds__(256) void xcvt(const float* __restrict__ x,
                                            ushort* __restrict__ xbf) {
    int i = blockIdx.x * 256 + threadIdx.x;
    float4 v = ((const float4*)x)[i];
    ushort4 p;
    p.x = f2bf(v.x); p.y = f2bf(v.y); p.z = f2bf(v.z); p.w = f2bf(v.w);
    ((ushort4*)xbf)[i] = p;
}

// ---------------- conv1: h = l2norm([mean|x] @ Wcat1^T + b1l), bf16 out ------
__global__ __launch_bounds__(256) void conv1_mfma(const ushort* __restrict__ mean,
                                                  const ushort* __restrict__ xbf,
                                                  const ushort* __restrict__ Wcat,
                                                  const float* __restrict__ bias,
                                                  ushort* __restrict__ h) {
    __shared__ char As[64 * 512];
    int m0 = blockIdx.x * 64;
    int tid = threadIdx.x;
    for (int c = tid; c < 2048; c += 256) {
        int m = c >> 5, kc = c & 31;
        int mm = min(m0 + m, NN - 1);
        uint4 v = (kc < 16) ? *(const uint4*)&mean[(size_t)mm * 128 + kc * 8]
                            : *(const uint4*)&xbf[(size_t)mm * 128 + (kc - 16) * 8];
        *(uint4*)(As + swz(m * 512 + kc * 16)) = v;
    }
    __syncthreads();

    int lane = tid & 63, wave = tid >> 6;
    int col = lane & 15, kg = lane >> 4;
    int mym = wave * 16 + col;
    short8 a[8];
#pragma unroll
    for (int ks = 0; ks < 8; ++ks)
        a[ks] = *(const short8*)(As + swz(mym * 512 + (ks * 32 + kg * 8) * 2));
    f32x4 acc[16];
#pragma unroll
    for (int nt = 0; nt < 16; ++nt) {
        f32x4 c = {0.f, 0.f, 0.f, 0.f};
        const ushort* wb = Wcat + (size_t)(nt * 16 + col) * 256 + kg * 8;
#pragma unroll
        for (int ks = 0; ks < 8; ++ks)
            c = __builtin_amdgcn_mfma_f32_16x16x32_bf16(a[ks], *(const short8*)(wb + ks * 32), c, 0, 0, 0);
        acc[nt] = c;
    }
    float ssq[4] = {0.f, 0.f, 0.f, 0.f};
#pragma unroll
    for (int nt = 0; nt < 16; ++nt) {
        float b = bias[nt * 16 + col];
#pragma unroll
        for (int r = 0; r < 4; ++r) {
            acc[nt][r] += b;
            ssq[r] += acc[nt][r] * acc[nt][r];
        }
    }
#pragma unroll
    for (int off = 1; off < 16; off <<= 1)
#pragma unroll
        for (int r = 0; r < 4; ++r) ssq[r] += __shfl_xor(ssq[r], off);
#pragma unroll
    for (int r = 0; r < 4; ++r) {
        int node = m0 + wave * 16 + kg * 4 + r;
        if (node < NN) {
            float rn = 1.0f / fmaxf(sqrtf(ssq[r]), 1e-12f);
#pragma unroll
            for (int nt = 0; nt < 16; ++nt)
                h[(size_t)node * 256 + nt * 16 + col] = f2bf(acc[nt][r] * rn);
        }
    }
}

// ---------------- linear+relu: hr = relu(h @ Wlin^T + blin), bf16 ----------
__global__ __launch_bounds__(256) void lin_mfma(const ushort* __restrict__ h,
                                                const ushort* __restrict__ W,
                                                const float* __restrict__ bias,
                                                ushort* __restrict__ hr) {
    __shared__ char As[64 * 512];
    int m0 = blockIdx.x * 64;
    int tid = threadIdx.x;
    for (int c = tid; c < 2048; c += 256) {
        int m = c >> 5, kc = c & 31;
        int mm = min(m0 + m, NN - 1);
        *(uint4*)(As + swz(m * 512 + kc * 16)) =
            *(const uint4*)&h[(size_t)mm * 256 + kc * 8];
    }
    __syncthreads();
    int lane = tid & 63, wave = tid >> 6;
    int col = lane & 15, kg = lane >> 4;
    int mym = wave * 16 + col;
    short8 a[8];
#pragma unroll
    for (int ks = 0; ks < 8; ++ks)
        a[ks] = *(const short8*)(As + swz(mym * 512 + (ks * 32 + kg * 8) * 2));
    f32x4 acc[8];
#pragma unroll
    for (int nt = 0; nt < 8; ++nt) {
        f32x4 c = {0.f, 0.f, 0.f, 0.f};
        const ushort* wb = W + (size_t)(nt * 16 + col) * 256 + kg * 8;
#pragma unroll
        for (int ks = 0; ks < 8; ++ks)
            c = __builtin_amdgcn_mfma_f32_16x16x32_bf16(a[ks], *(const short8*)(wb + ks * 32), c, 0, 0, 0);
        acc[nt] = c;
    }
#pragma unroll
    for (int r = 0; r < 4; ++r) {
        int node = m0 + wave * 16 + kg * 4 + r;
        if (node < NN) {
#pragma unroll
            for (int nt = 0; nt < 8; ++nt) {
                float v = acc[nt][r] + bias[nt * 16 + col];
                hr[(size_t)node * 128 + nt * 16 + col] = f2bf(fmaxf(v, 0.f));
            }
        }
    }
}

// ------- conv2 + linear2 + softmax: y = l2norm([mean2|hr]@Wcat2^T + b2l) -----
__global__ __launch_bounds__(256) void conv2_mfma(const ushort* __restrict__ mean,
                                                  const ushort* __restrict__ hr,
                                                  const ushort* __restrict__ Wcat,
                                                  const float* __restrict__ bias,
                                                  const float* __restrict__ Wlin2,
                                                  const float* __restrict__ blin2,
                                                  float* __restrict__ probs,
                                                  float* __restrict__ yout) {
    __shared__ char As[64 * 512];
    int m0 = blockIdx.x * 64;
    int tid = threadIdx.x;
    for (int c = tid; c < 2048; c += 256) {
        int m = c >> 5, kc = c & 31;
        int mm = min(m0 + m, NN - 1);
        uint4 v = (kc < 16) ? *(const uint4*)&mean[(size_t)mm * 128 + kc * 8]
                            : *(const uint4*)&hr[(size_t)mm * 128 + (kc - 16) * 8];
        *(uint4*)(As + swz(m * 512 + kc * 16)) = v;
    }
    __syncthreads();

    int lane = tid & 63, wave = tid >> 6;
    int col = lane & 15, kg = lane >> 4;
    int mym = wave * 16 + col;
    short8 a[8];
#pragma unroll
    for (int ks = 0; ks < 8; ++ks)
        a[ks] = *(const short8*)(As + swz(mym * 512 + (ks * 32 + kg * 8) * 2));
    f32x4 acc[8];
#pragma unroll
    for (int nt = 0; nt < 8; ++nt) {
        f32x4 c = {0.f, 0.f, 0.f, 0.f};
        const ushort* wb = Wcat + (size_t)(nt * 16 + col) * 256 + kg * 8;
#pragma unroll
        for (int ks = 0; ks < 8; ++ks)
            c = __builtin_amdgcn_mfma_f32_16x16x32_bf16(a[ks], *(const short8*)(wb + ks * 32), c, 0, 0, 0);
        acc[nt] = c;
    }
    float ssq[4] = {0.f, 0.f, 0.f, 0.f};
#pragma unroll
    for (int nt = 0; nt < 8; ++nt) {
        float b = bias[nt * 16 + col];
#pragma unroll
        for (int r = 0; r < 4; ++r) {
            acc[nt][r] += b;
            ssq[r] += acc[nt][r] * acc[nt][r];
        }
    }
#pragma unroll
    for (int off = 1; off < 16; off <<= 1)
#pragma unroll
        for (int r = 0; r < 4; ++r) ssq[r] += __shfl_xor(ssq[r], off);
    float rn[4], p0[4] = {0.f,0.f,0.f,0.f}, p1[4] = {0.f,0.f,0.f,0.f};
#pragma unroll
    for (int r = 0; r < 4; ++r) rn[r] = 1.0f / fmaxf(sqrtf(ssq[r]), 1e-12f);
#pragma unroll
    for (int nt = 0; nt < 8; ++nt) {
        float w0 = Wlin2[nt * 16 + col], w1 = Wlin2[128 + nt * 16 + col];
#pragma unroll
        for (int r = 0; r < 4; ++r) {
            float yv = acc[nt][r] * rn[r];
            acc[nt][r] = yv;
            p0[r] += yv * w0;
            p1[r] += yv * w1;
        }
    }
#pragma unroll
    for (int off = 1; off < 16; off <<= 1)
#pragma unroll
        for (int r = 0; r < 4; ++r) { p0[r] += __shfl_xor(p0[r], off); p1[r] += __shfl_xor(p1[r], off); }
#pragma unroll
    for (int r = 0; r < 4; ++r) {
        int node = m0 + wave * 16 + kg * 4 + r;
        if (node < NN) {
#pragma unroll
            for (int nt = 0; nt < 8; ++nt)
                yout[(size_t)node * 128 + nt * 16 + col] = acc[nt][r];
            if (col == 0) {
                float l0 = p0[r] + blin2[0], l1 = p1[r] + blin2[1];
                float mx = fmaxf(l0, l1);
                float e0 = expf(l0 - mx), e1 = expf(l1 - mx);
                float inv = 1.0f / (e0 + e1);
                probs[(size_t)node * 2 + 0] = e0 * inv;
                probs[(size_t)node * 2 + 1] = e1 * inv;
            }
        }
    }
}

extern "C" void kernel_launch(void* const* d_in, const int* in_sizes, int n_in,
                              void* d_out, int out_size, void* d_ws, size_t ws_size,
                              hipStream_t stream) {
    const float* x     = (const float*)d_in[0];
    const int*   ei    = (const int*)d_in[1];
    const int*   src   = ei;
    const int*   tgt   = ei + NE;
    const float* W1l   = (const float*)d_in[2];
    const float* b1l   = (const float*)d_in[3];
    const float* W1r   = (const float*)d_in[4];
    const float* Wlin  = (const float*)d_in[5];
    const float* blin  = (const float*)d_in[6];
    const float* W2l   = (const float*)d_in[7];
    const float* b2l   = (const float*)d_in[8];
    const float* W2r   = (const float*)d_in[9];
    const float* Wlin2 = (const float*)d_in[10];
    const float* blin2 = (const float*)d_in[11];

    float* probs = (float*)d_out;              // [N,2]
    float* y     = (float*)d_out + 2 * NN;     // [N,128]

    const int NB = (NN + 1023) / 1024;         // 98 scan blocks

    // ws layout
    int*    degi      = (int*)d_ws;                     // N
    int*    rowstart  = degi + NN;                      // N+1
    int*    cursor    = rowstart + NN + 1;              // N
    int*    bsum      = cursor + NN;                    // 128
    int*    sortedSrc = bsum + 128;                     // NE
    ushort* Wcat1     = (ushort*)(sortedSrc + NE);      // 256*256
    ushort* Wlinb     = Wcat1 + 65536;                  // 128*256
    ushort* Wcat2     = Wlinb + 32768;                  // 128*256
    ushort* xbf       = Wcat2 + 32768;                  // N*128 (later hr)
    ushort* h         = xbf + (size_t)NN * 128;         // N*256
    ushort* mean      = h + (size_t)NN * 256;           // N*128
    ushort* hr        = xbf;                            // reuse after conv1

    hipMemsetAsync(degi, 0, sizeof(int) * NN, stream);

    prep_w<<<512, 256, 0, stream>>>(W1l, W1r, Wlin, W2l, W2r, Wcat1, Wlinb, Wcat2);
    xcvt<<<NN * 32 / 256, 256, 0, stream>>>(x, xbf);

    hist_kernel<<<(NE + 255) / 256, 256, 0, stream>>>(tgt, degi);
    scan_reduce<<<NB, 256, 0, stream>>>(degi, bsum);
    scan_bsum<<<1, 128, 0, stream>>>(bsum, NB);
    scan_write<<<NB, 256, 0, stream>>>(degi, bsum, rowstart, cursor);
    fill_kernel<<<(NE + 255) / 256, 256, 0, stream>>>(src, tgt, cursor, sortedSrc);

    gather_mean<<<(NN + 3) / 4, 256, 0, stream>>>(xbf, rowstart, sortedSrc, mean);
    conv1_mfma<<<(NN + 63) / 64, 256, 0, stream>>>(mean, xbf, Wcat1, b1l, h);
    lin_mfma<<<(NN + 63) / 64, 256, 0, stream>>>(h, Wlinb, blin, hr);

    gather_mean<<<(NN + 3) / 4, 256, 0, stream>>>(hr, rowstart, sortedSrc, mean);
    conv2_mfma<<<(NN + 63) / 64, 256, 0, stream>>>(mean, hr, Wcat2, b2l,
                                                   Wlin2, blin2, probs, y);
}

// Round 5
// 491.574 us; speedup vs baseline: 24.3225x; 1.3249x over previous
//
#include <hip/hip_runtime.h>
#include <hip/hip_bf16.h>

#define NN   100000
#define NE   1600000

typedef __attribute__((ext_vector_type(8))) short short8;
typedef __attribute__((ext_vector_type(4))) float f32x4;

__device__ __forceinline__ ushort f2bf(float f) {
    union { float f; uint u; } v; v.f = f;
    uint u = v.u;
    return (ushort)((u + 0x7FFFu + ((u >> 16) & 1u)) >> 16);
}
__device__ __forceinline__ float bf2f(uint b) {
    union { uint u; float f; } v; v.u = b << 16;
    return v.f;
}
// XOR-swizzle for 512B-stride LDS rows (guide G4)
__device__ __forceinline__ int swz(int off) { return off ^ (((off >> 9) & 7) << 4); }

// ---------------- CSR build ----------------
__global__ __launch_bounds__(256) void hist_kernel(const int* __restrict__ tgt,
                                                   int* __restrict__ degi) {
    int e4 = blockIdx.x * 256 + threadIdx.x;
    if (e4 < NE / 4) {
        int4 t = ((const int4*)tgt)[e4];
        atomicAdd(&degi[t.x], 1); atomicAdd(&degi[t.y], 1);
        atomicAdd(&degi[t.z], 1); atomicAdd(&degi[t.w], 1);
    }
}

// phase 1: per-1024-node block sums
__global__ __launch_bounds__(256) void scan_reduce(const int* __restrict__ degi,
                                                   int* __restrict__ bsum) {
    int b = blockIdx.x, t = threadIdx.x;
    int i0 = b * 1024 + t * 4;
    int s = 0;
    if (i0 + 3 < NN) {
        int4 v = *(const int4*)&degi[i0];
        s = v.x + v.y + v.z + v.w;
    } else {
        for (int k = 0; k < 4; ++k) if (i0 + k < NN) s += degi[i0 + k];
    }
    int lane = t & 63, wid = t >> 6;
#pragma unroll
    for (int off = 32; off >= 1; off >>= 1) s += __shfl_xor(s, off);
    __shared__ int ws[4];
    if (lane == 0) ws[wid] = s;
    __syncthreads();
    if (t == 0) bsum[b] = ws[0] + ws[1] + ws[2] + ws[3];
}

// phase 2: exclusive scan of block sums (nb <= 128), single block
__global__ __launch_bounds__(128) void scan_bsum(int* __restrict__ bsum, int nb) {
    int t = threadIdx.x;
    int v = (t < nb) ? bsum[t] : 0;
    int lane = t & 63, wid = t >> 6;
    int inc = v;
#pragma unroll
    for (int off = 1; off < 64; off <<= 1) {
        int u = __shfl_up(inc, off);
        if (lane >= off) inc += u;
    }
    __shared__ int ws[2];
    if (lane == 63) ws[wid] = inc;
    __syncthreads();
    int add = (wid == 1) ? ws[0] : 0;
    if (t < nb) bsum[t] = inc - v + add;    // exclusive
}

// phase 3: per-block local scan + offset, write rowstart & cursor
__global__ __launch_bounds__(256) void scan_write(const int* __restrict__ degi,
                                                  const int* __restrict__ bsum,
                                                  int* __restrict__ rowstart,
                                                  int* __restrict__ cursor) {
    int b = blockIdx.x, t = threadIdx.x;
    int i0 = b * 1024 + t * 4;
    int d[4] = {0, 0, 0, 0};
    if (i0 + 3 < NN) {
        int4 v = *(const int4*)&degi[i0];
        d[0] = v.x; d[1] = v.y; d[2] = v.z; d[3] = v.w;
    } else {
        for (int k = 0; k < 4; ++k) if (i0 + k < NN) d[k] = degi[i0 + k];
    }
    int s = d[0] + d[1] + d[2] + d[3];
    int lane = t & 63, wid = t >> 6;
    int inc = s;
#pragma unroll
    for (int off = 1; off < 64; off <<= 1) {
        int u = __shfl_up(inc, off);
        if (lane >= off) inc += u;
    }
    __shared__ int ws[4];
    if (lane == 63) ws[wid] = inc;
    __syncthreads();
    int woff = 0;
    for (int w = 0; w < wid; ++w) woff += ws[w];
    int ex = inc - s + woff + bsum[b];
    for (int k = 0; k < 4; ++k) {
        int idx = i0 + k;
        if (idx < NN) {
            rowstart[idx] = ex; cursor[idx] = ex;
            ex += d[k];
            if (idx == NN - 1) rowstart[NN] = ex;
        }
    }
}

__global__ __launch_bounds__(256) void fill_kernel(const int* __restrict__ src,
                                                   const int* __restrict__ tgt,
                                                   int* __restrict__ cursor,
                                                   int* __restrict__ sortedSrc) {
    int e4 = blockIdx.x * 256 + threadIdx.x;
    if (e4 < NE / 4) {
        int4 t = ((const int4*)tgt)[e4];
        int4 s = ((const int4*)src)[e4];
        int p0 = atomicAdd(&cursor[t.x], 1); sortedSrc[p0] = s.x;
        int p1 = atomicAdd(&cursor[t.y], 1); sortedSrc[p1] = s.y;
        int p2 = atomicAdd(&cursor[t.z], 1); sortedSrc[p2] = s.z;
        int p3 = atomicAdd(&cursor[t.w], 1); sortedSrc[p3] = s.w;
    }
}

// ------ gather mean: wave per node, quarter-wave per edge, 16B/lane, x2 -----
__global__ __launch_bounds__(256) void gather_mean(const ushort* __restrict__ xin,
                                                   const int* __restrict__ rowstart,
                                                   const int* __restrict__ sortedSrc,
                                                   ushort* __restrict__ mean) {
    int node = blockIdx.x * 4 + (threadIdx.x >> 6);
    if (node >= NN) return;
    int lane = threadIdx.x & 63;
    int q = lane >> 4, l = lane & 15;
    int beg = rowstart[node], end = rowstart[node + 1];
    float a0 = 0.f, a1 = 0.f, a2 = 0.f, a3 = 0.f;
    float a4 = 0.f, a5 = 0.f, a6 = 0.f, a7 = 0.f;
    int i = beg + q;
    for (; i + 4 < end; i += 8) {
        int s0 = sortedSrc[i];
        int s1 = sortedSrc[i + 4];
        uint4 v0 = *(const uint4*)&xin[(size_t)s0 * 128 + l * 8];
        uint4 v1 = *(const uint4*)&xin[(size_t)s1 * 128 + l * 8];
        a0 += bf2f(v0.x & 0xffffu) + bf2f(v1.x & 0xffffu);
        a1 += bf2f(v0.x >> 16)     + bf2f(v1.x >> 16);
        a2 += bf2f(v0.y & 0xffffu) + bf2f(v1.y & 0xffffu);
        a3 += bf2f(v0.y >> 16)     + bf2f(v1.y >> 16);
        a4 += bf2f(v0.z & 0xffffu) + bf2f(v1.z & 0xffffu);
        a5 += bf2f(v0.z >> 16)     + bf2f(v1.z >> 16);
        a6 += bf2f(v0.w & 0xffffu) + bf2f(v1.w & 0xffffu);
        a7 += bf2f(v0.w >> 16)     + bf2f(v1.w >> 16);
    }
    if (i < end) {
        int s0 = sortedSrc[i];
        uint4 v0 = *(const uint4*)&xin[(size_t)s0 * 128 + l * 8];
        a0 += bf2f(v0.x & 0xffffu); a1 += bf2f(v0.x >> 16);
        a2 += bf2f(v0.y & 0xffffu); a3 += bf2f(v0.y >> 16);
        a4 += bf2f(v0.z & 0xffffu); a5 += bf2f(v0.z >> 16);
        a6 += bf2f(v0.w & 0xffffu); a7 += bf2f(v0.w >> 16);
    }
#define CMB(a) a += __shfl_xor(a, 32); a += __shfl_xor(a, 16);
    CMB(a0) CMB(a1) CMB(a2) CMB(a3) CMB(a4) CMB(a5) CMB(a6) CMB(a7)
#undef CMB
    if (lane < 16) {
        float id = 1.0f / fmaxf((float)(end - beg), 1.0f);
        ushort p[8];
        p[0] = f2bf(a0 * id); p[1] = f2bf(a1 * id);
        p[2] = f2bf(a2 * id); p[3] = f2bf(a3 * id);
        p[4] = f2bf(a4 * id); p[5] = f2bf(a5 * id);
        p[6] = f2bf(a6 * id); p[7] = f2bf(a7 * id);
        *(uint4*)&mean[(size_t)node * 128 + l * 8] = *(uint4*)p;
    }
}

// ---------------- weight prep: fp32 -> bf16, concat [Wl|Wr] ----------------
__global__ __launch_bounds__(256) void prep_w(const float* __restrict__ W1l,
                                              const float* __restrict__ W1r,
                                              const float* __restrict__ Wlin,
                                              const float* __restrict__ W2l,
                                              const float* __restrict__ W2r,
                                              ushort* __restrict__ Wcat1,
                                              ushort* __restrict__ Wlinb,
                                              ushort* __restrict__ Wcat2) {
    int i = blockIdx.x * 256 + threadIdx.x;
    if (i < 65536) {               // Wcat1 [256][256]
        int o = i >> 8, k = i & 255;
        float v = (k < 128) ? W1l[o * 128 + k] : W1r[o * 128 + k - 128];
        Wcat1[i] = f2bf(v);
    } else if (i < 98304) {        // Wlin [128][256]
        int j = i - 65536;
        Wlinb[j] = f2bf(Wlin[j]);
    } else {                       // Wcat2 [128][256]
        int j = i - 98304;
        int o = j >> 8, k = j & 255;
        float v = (k < 128) ? W2l[o * 128 + k] : W2r[o * 128 + k - 128];
        Wcat2[j] = f2bf(v);
    }
}

// ---------------- x fp32 -> bf16 ----------------
__global__ __launch_bounds__(256) void xcvt(const float* __restrict__ x,
                                            ushort* __restrict__ xbf) {
    int i = blockIdx.x * 256 + threadIdx.x;
    float4 v = ((const float4*)x)[i];
    ushort4 p;
    p.x = f2bf(v.x); p.y = f2bf(v.y); p.z = f2bf(v.z); p.w = f2bf(v.w);
    ((ushort4*)xbf)[i] = p;
}

// ---------------- conv1: h = l2norm([mean|x] @ Wcat1^T + b1l), bf16 out ------
// 64 nodes/block; weights staged in LDS in 4 chunks of 64 outputs
__global__ __launch_bounds__(256) void conv1_mfma(const ushort* __restrict__ mean,
                                                  const ushort* __restrict__ xbf,
                                                  const ushort* __restrict__ Wcat,
                                                  const float* __restrict__ bias,
                                                  ushort* __restrict__ h) {
    __shared__ char As[64 * 512];
    __shared__ char Bs[64 * 512];
    int m0 = blockIdx.x * 64;
    int tid = threadIdx.x;
    for (int c = tid; c < 2048; c += 256) {
        int m = c >> 5, kc = c & 31;
        int mm = min(m0 + m, NN - 1);
        uint4 v = (kc < 16) ? *(const uint4*)&mean[(size_t)mm * 128 + kc * 8]
                            : *(const uint4*)&xbf[(size_t)mm * 128 + (kc - 16) * 8];
        *(uint4*)(As + swz(m * 512 + kc * 16)) = v;
    }
    for (int j = tid; j < 2048; j += 256)
        *(uint4*)(Bs + swz((j >> 5) * 512 + (j & 31) * 16)) = *(const uint4*)&Wcat[j * 8];
    __syncthreads();

    int lane = tid & 63, wave = tid >> 6;
    int col = lane & 15, kg = lane >> 4;
    int mym = wave * 16 + col;
    short8 a[8];
#pragma unroll
    for (int ks = 0; ks < 8; ++ks)
        a[ks] = *(const short8*)(As + swz(mym * 512 + (ks * 32 + kg * 8) * 2));
    f32x4 acc[16];
#pragma unroll
    for (int nt = 0; nt < 4; ++nt) {
        f32x4 c = {0.f, 0.f, 0.f, 0.f};
#pragma unroll
        for (int ks = 0; ks < 8; ++ks)
            c = __builtin_amdgcn_mfma_f32_16x16x32_bf16(
                a[ks], *(const short8*)(Bs + swz((nt * 16 + col) * 512 + (ks * 32 + kg * 8) * 2)), c, 0, 0, 0);
        acc[nt] = c;
    }
    for (int ch = 1; ch < 4; ++ch) {
        __syncthreads();
        for (int j = tid; j < 2048; j += 256)
            *(uint4*)(Bs + swz((j >> 5) * 512 + (j & 31) * 16)) =
                *(const uint4*)&Wcat[ch * 16384 + j * 8];
        __syncthreads();
#pragma unroll
        for (int nt = 0; nt < 4; ++nt) {
            f32x4 c = {0.f, 0.f, 0.f, 0.f};
#pragma unroll
            for (int ks = 0; ks < 8; ++ks)
                c = __builtin_amdgcn_mfma_f32_16x16x32_bf16(
                    a[ks], *(const short8*)(Bs + swz((nt * 16 + col) * 512 + (ks * 32 + kg * 8) * 2)), c, 0, 0, 0);
            acc[ch * 4 + nt] = c;
        }
    }
    float ssq[4] = {0.f, 0.f, 0.f, 0.f};
#pragma unroll
    for (int nt = 0; nt < 16; ++nt) {
        float b = bias[nt * 16 + col];
#pragma unroll
        for (int r = 0; r < 4; ++r) {
            acc[nt][r] += b;
            ssq[r] += acc[nt][r] * acc[nt][r];
        }
    }
#pragma unroll
    for (int off = 1; off < 16; off <<= 1)
#pragma unroll
        for (int r = 0; r < 4; ++r) ssq[r] += __shfl_xor(ssq[r], off);
#pragma unroll
    for (int r = 0; r < 4; ++r) {
        int node = m0 + wave * 16 + kg * 4 + r;
        if (node < NN) {
            float rn = 1.0f / fmaxf(sqrtf(ssq[r]), 1e-12f);
#pragma unroll
            for (int nt = 0; nt < 16; ++nt)
                h[(size_t)node * 256 + nt * 16 + col] = f2bf(acc[nt][r] * rn);
        }
    }
}

// ---------------- linear+relu: hr = relu(h @ Wlin^T + blin), bf16 ----------
__global__ __launch_bounds__(256) void lin_mfma(const ushort* __restrict__ h,
                                                const ushort* __restrict__ W,
                                                const float* __restrict__ bias,
                                                ushort* __restrict__ hr) {
    __shared__ char As[64 * 512];
    __shared__ char Bs[64 * 512];
    int m0 = blockIdx.x * 64;
    int tid = threadIdx.x;
    for (int c = tid; c < 2048; c += 256) {
        int m = c >> 5, kc = c & 31;
        int mm = min(m0 + m, NN - 1);
        *(uint4*)(As + swz(m * 512 + kc * 16)) =
            *(const uint4*)&h[(size_t)mm * 256 + kc * 8];
    }
    for (int j = tid; j < 2048; j += 256)
        *(uint4*)(Bs + swz((j >> 5) * 512 + (j & 31) * 16)) = *(const uint4*)&W[j * 8];
    __syncthreads();
    int lane = tid & 63, wave = tid >> 6;
    int col = lane & 15, kg = lane >> 4;
    int mym = wave * 16 + col;
    short8 a[8];
#pragma unroll
    for (int ks = 0; ks < 8; ++ks)
        a[ks] = *(const short8*)(As + swz(mym * 512 + (ks * 32 + kg * 8) * 2));
    f32x4 acc[8];
#pragma unroll
    for (int nt = 0; nt < 4; ++nt) {
        f32x4 c = {0.f, 0.f, 0.f, 0.f};
#pragma unroll
        for (int ks = 0; ks < 8; ++ks)
            c = __builtin_amdgcn_mfma_f32_16x16x32_bf16(
                a[ks], *(const short8*)(Bs + swz((nt * 16 + col) * 512 + (ks * 32 + kg * 8) * 2)), c, 0, 0, 0);
        acc[nt] = c;
    }
    __syncthreads();
    for (int j = tid; j < 2048; j += 256)
        *(uint4*)(Bs + swz((j >> 5) * 512 + (j & 31) * 16)) = *(const uint4*)&W[16384 + j * 8];
    __syncthreads();
#pragma unroll
    for (int nt = 0; nt < 4; ++nt) {
        f32x4 c = {0.f, 0.f, 0.f, 0.f};
#pragma unroll
        for (int ks = 0; ks < 8; ++ks)
            c = __builtin_amdgcn_mfma_f32_16x16x32_bf16(
                a[ks], *(const short8*)(Bs + swz((nt * 16 + col) * 512 + (ks * 32 + kg * 8) * 2)), c, 0, 0, 0);
        acc[4 + nt] = c;
    }
#pragma unroll
    for (int r = 0; r < 4; ++r) {
        int node = m0 + wave * 16 + kg * 4 + r;
        if (node < NN) {
#pragma unroll
            for (int nt = 0; nt < 8; ++nt) {
                float v = acc[nt][r] + bias[nt * 16 + col];
                hr[(size_t)node * 128 + nt * 16 + col] = f2bf(fmaxf(v, 0.f));
            }
        }
    }
}

// ------- conv2 + linear2 + softmax: y = l2norm([mean2|hr]@Wcat2^T + b2l) -----
__global__ __launch_bounds__(256) void conv2_mfma(const ushort* __restrict__ mean,
                                                  const ushort* __restrict__ hr,
                                                  const ushort* __restrict__ Wcat,
                                                  const float* __restrict__ bias,
                                                  const float* __restrict__ Wlin2,
                                                  const float* __restrict__ blin2,
                                                  float* __restrict__ probs,
                                                  float* __restrict__ yout) {
    __shared__ char As[64 * 512];
    __shared__ char Bs[64 * 512];
    int m0 = blockIdx.x * 64;
    int tid = threadIdx.x;
    for (int c = tid; c < 2048; c += 256) {
        int m = c >> 5, kc = c & 31;
        int mm = min(m0 + m, NN - 1);
        uint4 v = (kc < 16) ? *(const uint4*)&mean[(size_t)mm * 128 + kc * 8]
                            : *(const uint4*)&hr[(size_t)mm * 128 + (kc - 16) * 8];
        *(uint4*)(As + swz(m * 512 + kc * 16)) = v;
    }
    for (int j = tid; j < 2048; j += 256)
        *(uint4*)(Bs + swz((j >> 5) * 512 + (j & 31) * 16)) = *(const uint4*)&Wcat[j * 8];
    __syncthreads();

    int lane = tid & 63, wave = tid >> 6;
    int col = lane & 15, kg = lane >> 4;
    int mym = wave * 16 + col;
    short8 a[8];
#pragma unroll
    for (int ks = 0; ks < 8; ++ks)
        a[ks] = *(const short8*)(As + swz(mym * 512 + (ks * 32 + kg * 8) * 2));
    f32x4 acc[8];
#pragma unroll
    for (int nt = 0; nt < 4; ++nt) {
        f32x4 c = {0.f, 0.f, 0.f, 0.f};
#pragma unroll
        for (int ks = 0; ks < 8; ++ks)
            c = __builtin_amdgcn_mfma_f32_16x16x32_bf16(
                a[ks], *(const short8*)(Bs + swz((nt * 16 + col) * 512 + (ks * 32 + kg * 8) * 2)), c, 0, 0, 0);
        acc[nt] = c;
    }
    __syncthreads();
    for (int j = tid; j < 2048; j += 256)
        *(uint4*)(Bs + swz((j >> 5) * 512 + (j & 31) * 16)) = *(const uint4*)&Wcat[16384 + j * 8];
    __syncthreads();
#pragma unroll
    for (int nt = 0; nt < 4; ++nt) {
        f32x4 c = {0.f, 0.f, 0.f, 0.f};
#pragma unroll
        for (int ks = 0; ks < 8; ++ks)
            c = __builtin_amdgcn_mfma_f32_16x16x32_bf16(
                a[ks], *(const short8*)(Bs + swz((nt * 16 + col) * 512 + (ks * 32 + kg * 8) * 2)), c, 0, 0, 0);
        acc[4 + nt] = c;
    }
    float ssq[4] = {0.f, 0.f, 0.f, 0.f};
#pragma unroll
    for (int nt = 0; nt < 8; ++nt) {
        float b = bias[nt * 16 + col];
#pragma unroll
        for (int r = 0; r < 4; ++r) {
            acc[nt][r] += b;
            ssq[r] += acc[nt][r] * acc[nt][r];
        }
    }
#pragma unroll
    for (int off = 1; off < 16; off <<= 1)
#pragma unroll
        for (int r = 0; r < 4; ++r) ssq[r] += __shfl_xor(ssq[r], off);
    float rn[4], p0[4] = {0.f,0.f,0.f,0.f}, p1[4] = {0.f,0.f,0.f,0.f};
#pragma unroll
    for (int r = 0; r < 4; ++r) rn[r] = 1.0f / fmaxf(sqrtf(ssq[r]), 1e-12f);
#pragma unroll
    for (int nt = 0; nt < 8; ++nt) {
        float w0 = Wlin2[nt * 16 + col], w1 = Wlin2[128 + nt * 16 + col];
#pragma unroll
        for (int r = 0; r < 4; ++r) {
            float yv = acc[nt][r] * rn[r];
            acc[nt][r] = yv;
            p0[r] += yv * w0;
            p1[r] += yv * w1;
        }
    }
#pragma unroll
    for (int off = 1; off < 16; off <<= 1)
#pragma unroll
        for (int r = 0; r < 4; ++r) { p0[r] += __shfl_xor(p0[r], off); p1[r] += __shfl_xor(p1[r], off); }
#pragma unroll
    for (int r = 0; r < 4; ++r) {
        int node = m0 + wave * 16 + kg * 4 + r;
        if (node < NN) {
#pragma unroll
            for (int nt = 0; nt < 8; ++nt)
                yout[(size_t)node * 128 + nt * 16 + col] = acc[nt][r];
            if (col == 0) {
                float l0 = p0[r] + blin2[0], l1 = p1[r] + blin2[1];
                float mx = fmaxf(l0, l1);
                float e0 = expf(l0 - mx), e1 = expf(l1 - mx);
                float inv = 1.0f / (e0 + e1);
                probs[(size_t)node * 2 + 0] = e0 * inv;
                probs[(size_t)node * 2 + 1] = e1 * inv;
            }
        }
    }
}

extern "C" void kernel_launch(void* const* d_in, const int* in_sizes, int n_in,
                              void* d_out, int out_size, void* d_ws, size_t ws_size,
                              hipStream_t stream) {
    const float* x     = (const float*)d_in[0];
    const int*   ei    = (const int*)d_in[1];
    const int*   src   = ei;
    const int*   tgt   = ei + NE;
    const float* W1l   = (const float*)d_in[2];
    const float* b1l   = (const float*)d_in[3];
    const float* W1r   = (const float*)d_in[4];
    const float* Wlin  = (const float*)d_in[5];
    const float* blin  = (const float*)d_in[6];
    const float* W2l   = (const float*)d_in[7];
    const float* b2l   = (const float*)d_in[8];
    const float* W2r   = (const float*)d_in[9];
    const float* Wlin2 = (const float*)d_in[10];
    const float* blin2 = (const float*)d_in[11];

    float* probs = (float*)d_out;              // [N,2]
    float* y     = (float*)d_out + 2 * NN;     // [N,128]

    const int NB = (NN + 1023) / 1024;         // 98 scan blocks

    // ws layout
    int*    degi      = (int*)d_ws;                     // N
    int*    rowstart  = degi + NN;                      // N+1
    int*    cursor    = rowstart + NN + 1;              // N
    int*    bsum      = cursor + NN;                    // 128
    int*    sortedSrc = bsum + 128;                     // NE
    ushort* Wcat1     = (ushort*)(sortedSrc + NE);      // 256*256
    ushort* Wlinb     = Wcat1 + 65536;                  // 128*256
    ushort* Wcat2     = Wlinb + 32768;                  // 128*256
    ushort* xbf       = Wcat2 + 32768;                  // N*128 (later hr)
    ushort* h         = xbf + (size_t)NN * 128;         // N*256
    ushort* mean      = h + (size_t)NN * 256;           // N*128
    ushort* hr        = xbf;                            // reuse after conv1

    hipMemsetAsync(degi, 0, sizeof(int) * NN, stream);

    prep_w<<<512, 256, 0, stream>>>(W1l, W1r, Wlin, W2l, W2r, Wcat1, Wlinb, Wcat2);
    xcvt<<<NN * 32 / 256, 256, 0, stream>>>(x, xbf);

    hist_kernel<<<(NE / 4 + 255) / 256, 256, 0, stream>>>(tgt, degi);
    scan_reduce<<<NB, 256, 0, stream>>>(degi, bsum);
    scan_bsum<<<1, 128, 0, stream>>>(bsum, NB);
    scan_write<<<NB, 256, 0, stream>>>(degi, bsum, rowstart, cursor);
    fill_kernel<<<(NE / 4 + 255) / 256, 256, 0, stream>>>(src, tgt, cursor, sortedSrc);

    gather_mean<<<(NN + 3) / 4, 256, 0, stream>>>(xbf, rowstart, sortedSrc, mean);
    conv1_mfma<<<(NN + 63) / 64, 256, 0, stream>>>(mean, xbf, Wcat1, b1l, h);
    lin_mfma<<<(NN + 63) / 64, 256, 0, stream>>>(h, Wlinb, blin, hr);

    gather_mean<<<(NN + 3) / 4, 256, 0, stream>>>(hr, rowstart, sortedSrc, mean);
    conv2_mfma<<<(NN + 63) / 64, 256, 0, stream>>>(mean, hr, Wcat2, b2l,
                                                   Wlin2, blin2, probs, y);
}

// Round 6
// 340.261 us; speedup vs baseline: 35.1387x; 1.4447x over previous
//
#include <hip/hip_runtime.h>
#include <hip/hip_bf16.h>

#define NN   100000
#define NE   1600000
#define NBK  196      // ceil(NN/512) buckets
#define BSH  9        // 512 nodes per bucket
#define EPB  8192     // edges per scatter block
#define CAP  9216     // max edges per bucket (mean 8192 + 11 sigma)

typedef __attribute__((ext_vector_type(8))) short short8;
typedef __attribute__((ext_vector_type(4))) float f32x4;

__device__ __forceinline__ ushort f2bf(float f) {
    union { float f; uint u; } v; v.f = f;
    uint u = v.u;
    return (ushort)((u + 0x7FFFu + ((u >> 16) & 1u)) >> 16);
}
__device__ __forceinline__ float bf2f(uint b) {
    union { uint u; float f; } v; v.u = b << 16;
    return v.f;
}
// XOR-swizzle for 512B-stride LDS rows (guide G4)
__device__ __forceinline__ int swz(int off) { return off ^ (((off >> 9) & 7) << 4); }

// ---------------- bucket histogram (LDS pre-aggregated) ----------------
__global__ __launch_bounds__(256) void bucket_hist(const int* __restrict__ tgt,
                                                   int* __restrict__ bcnt) {
    __shared__ int lh[NBK];
    int tid = threadIdx.x;
    for (int i = tid; i < NBK; i += 256) lh[i] = 0;
    __syncthreads();
    int base4 = blockIdx.x * (EPB / 4);
#pragma unroll
    for (int k = 0; k < 8; ++k) {
        int i4 = base4 + k * 256 + tid;
        if (i4 < NE / 4) {
            int4 t = ((const int4*)tgt)[i4];
            atomicAdd(&lh[t.x >> BSH], 1);
            atomicAdd(&lh[t.y >> BSH], 1);
            atomicAdd(&lh[t.z >> BSH], 1);
            atomicAdd(&lh[t.w >> BSH], 1);
        }
    }
    __syncthreads();
    for (int i = tid; i < NBK; i += 256)
        if (lh[i]) atomicAdd(&bcnt[i], lh[i]);
}

// ---------------- bucket scan (196 values, 1 block) ----------------
__global__ __launch_bounds__(256) void bucket_scan(const int* __restrict__ bcnt,
                                                   int* __restrict__ bbase,
                                                   int* __restrict__ bcursor,
                                                   int* __restrict__ rowstart) {
    int t = threadIdx.x;
    int v = (t < NBK) ? bcnt[t] : 0;
    int lane = t & 63, wid = t >> 6;
    int inc = v;
#pragma unroll
    for (int off = 1; off < 64; off <<= 1) {
        int u = __shfl_up(inc, off);
        if (lane >= off) inc += u;
    }
    __shared__ int ws[4];
    if (lane == 63) ws[wid] = inc;
    __syncthreads();
    int woff = 0;
    for (int w = 0; w < wid; ++w) woff += ws[w];
    int ex = woff + inc - v;
    if (t < NBK) { bbase[t] = ex; bcursor[t] = ex; }
    if (t == NBK) bbase[NBK] = ex;      // == NE
    if (t == 255) rowstart[NN] = NE;
}

// ------- bucket scatter: block-local order by bucket, coalesced runs -------
__global__ __launch_bounds__(256) void bucket_scatter(const int* __restrict__ src,
                                                      const int* __restrict__ tgt,
                                                      int* __restrict__ bcursor,
                                                      uint* __restrict__ brec) {
    __shared__ int lh[NBK + 1];
    __shared__ int lcur[NBK];
    __shared__ int lbase[NBK];
    __shared__ uint lrec[EPB];
    __shared__ int ws[4];
    int tid = threadIdx.x;
    for (int i = tid; i < NBK; i += 256) lh[i] = 0;
    __syncthreads();
    int base4 = blockIdx.x * (EPB / 4);
#pragma unroll
    for (int k = 0; k < 8; ++k) {
        int i4 = base4 + k * 256 + tid;
        if (i4 < NE / 4) {
            int4 t = ((const int4*)tgt)[i4];
            atomicAdd(&lh[t.x >> BSH], 1);
            atomicAdd(&lh[t.y >> BSH], 1);
            atomicAdd(&lh[t.z >> BSH], 1);
            atomicAdd(&lh[t.w >> BSH], 1);
        }
    }
    __syncthreads();
    // exclusive scan of lh[0..NBK)
    int v = (tid < NBK) ? lh[tid] : 0;
    int lane = tid & 63, wid = tid >> 6;
    int inc = v;
#pragma unroll
    for (int off = 1; off < 64; off <<= 1) {
        int u = __shfl_up(inc, off);
        if (lane >= off) inc += u;
    }
    if (lane == 63) ws[wid] = inc;
    __syncthreads();                      // also orders all lh reads before overwrite
    int woff = 0;
    for (int w = 0; w < wid; ++w) woff += ws[w];
    int ex = woff + inc - v;
    int nval = min(EPB, NE - blockIdx.x * EPB);
    if (tid < NBK) {
        lh[tid] = ex;                     // segment starts (immutable copy)
        lcur[tid] = ex;                   // placement cursor
        lbase[tid] = v ? atomicAdd(&bcursor[tid], v) : 0;  // reserve global run
    }
    if (tid == 0) lh[NBK] = nval;
    __syncthreads();
    // place records into LDS ordered by bucket
#pragma unroll
    for (int k = 0; k < 8; ++k) {
        int i4 = base4 + k * 256 + tid;
        if (i4 < NE / 4) {
            int4 t = ((const int4*)tgt)[i4];
            int4 s = ((const int4*)src)[i4];
            int p;
            p = atomicAdd(&lcur[t.x >> BSH], 1); lrec[p] = ((uint)s.x << BSH) | (uint)(t.x & 511);
            p = atomicAdd(&lcur[t.y >> BSH], 1); lrec[p] = ((uint)s.y << BSH) | (uint)(t.y & 511);
            p = atomicAdd(&lcur[t.z >> BSH], 1); lrec[p] = ((uint)s.z << BSH) | (uint)(t.z & 511);
            p = atomicAdd(&lcur[t.w >> BSH], 1); lrec[p] = ((uint)s.w << BSH) | (uint)(t.w & 511);
        }
    }
    __syncthreads();
    // coalesced write-out (consecutive i -> consecutive global within runs)
    for (int i = tid; i < nval; i += 256) {
        int lo = 0, hi = NBK;
        while (hi - lo > 1) { int mid = (lo + hi) >> 1; if (lh[mid] <= i) lo = mid; else hi = mid; }
        brec[lbase[lo] + (i - lh[lo])] = lrec[i];
    }
}

// ------- bucket -> CSR: per-bucket node sort in LDS, coalesced output -------
__global__ __launch_bounds__(256) void bucket_to_csr(const uint* __restrict__ brec,
                                                     const int* __restrict__ bbase,
                                                     int* __restrict__ rowstart,
                                                     int* __restrict__ sortedSrc) {
    __shared__ int cnt[512];
    __shared__ int cur[512];
    __shared__ int srt[CAP];
    __shared__ int ws[4];
    int b = blockIdx.x;
    int beg = bbase[b], end = bbase[b + 1];
    int len = end - beg;
    int n0 = b << BSH;
    int ncnt = min(512, NN - n0);
    int tid = threadIdx.x;
    cnt[tid] = 0; cnt[tid + 256] = 0;
    __syncthreads();
    for (int i = beg + tid; i < end; i += 256)
        atomicAdd(&cnt[brec[i] & 511u], 1);
    __syncthreads();
    int c0 = cnt[2 * tid], c1 = cnt[2 * tid + 1];
    int s = c0 + c1;
    int lane = tid & 63, wid = tid >> 6;
    int inc = s;
#pragma unroll
    for (int off = 1; off < 64; off <<= 1) {
        int u = __shfl_up(inc, off);
        if (lane >= off) inc += u;
    }
    if (lane == 63) ws[wid] = inc;
    __syncthreads();
    int woff = 0;
    for (int w = 0; w < wid; ++w) woff += ws[w];
    int ex = woff + inc - s;
    cur[2 * tid] = ex; cur[2 * tid + 1] = ex + c0;
    if (2 * tid < ncnt)     rowstart[n0 + 2 * tid]     = beg + ex;
    if (2 * tid + 1 < ncnt) rowstart[n0 + 2 * tid + 1] = beg + ex + c0;
    __syncthreads();
    if (len <= CAP) {
        for (int i = beg + tid; i < end; i += 256) {
            uint r = brec[i];
            int p = atomicAdd(&cur[r & 511u], 1);
            srt[p] = (int)(r >> BSH);
        }
        __syncthreads();
        for (int i = tid; i < len; i += 256)
            sortedSrc[beg + i] = srt[i];
    } else {  // safety fallback (statistically unreachable)
        for (int i = beg + tid; i < end; i += 256) {
            uint r = brec[i];
            int p = atomicAdd(&cur[r & 511u], 1);
            sortedSrc[beg + p] = (int)(r >> BSH);
        }
    }
}

// ------ gather mean: wave per node, quarter-wave per edge, 16B/lane, x2 -----
__global__ __launch_bounds__(256) void gather_mean(const ushort* __restrict__ xin,
                                                   const int* __restrict__ rowstart,
                                                   const int* __restrict__ sortedSrc,
                                                   ushort* __restrict__ mean) {
    int node = blockIdx.x * 4 + (threadIdx.x >> 6);
    if (node >= NN) return;
    int lane = threadIdx.x & 63;
    int q = lane >> 4, l = lane & 15;
    int beg = rowstart[node], end = rowstart[node + 1];
    float a0 = 0.f, a1 = 0.f, a2 = 0.f, a3 = 0.f;
    float a4 = 0.f, a5 = 0.f, a6 = 0.f, a7 = 0.f;
    int i = beg + q;
    for (; i + 4 < end; i += 8) {
        int s0 = sortedSrc[i];
        int s1 = sortedSrc[i + 4];
        uint4 v0 = *(const uint4*)&xin[(size_t)s0 * 128 + l * 8];
        uint4 v1 = *(const uint4*)&xin[(size_t)s1 * 128 + l * 8];
        a0 += bf2f(v0.x & 0xffffu) + bf2f(v1.x & 0xffffu);
        a1 += bf2f(v0.x >> 16)     + bf2f(v1.x >> 16);
        a2 += bf2f(v0.y & 0xffffu) + bf2f(v1.y & 0xffffu);
        a3 += bf2f(v0.y >> 16)     + bf2f(v1.y >> 16);
        a4 += bf2f(v0.z & 0xffffu) + bf2f(v1.z & 0xffffu);
        a5 += bf2f(v0.z >> 16)     + bf2f(v1.z >> 16);
        a6 += bf2f(v0.w & 0xffffu) + bf2f(v1.w & 0xffffu);
        a7 += bf2f(v0.w >> 16)     + bf2f(v1.w >> 16);
    }
    if (i < end) {
        int s0 = sortedSrc[i];
        uint4 v0 = *(const uint4*)&xin[(size_t)s0 * 128 + l * 8];
        a0 += bf2f(v0.x & 0xffffu); a1 += bf2f(v0.x >> 16);
        a2 += bf2f(v0.y & 0xffffu); a3 += bf2f(v0.y >> 16);
        a4 += bf2f(v0.z & 0xffffu); a5 += bf2f(v0.z >> 16);
        a6 += bf2f(v0.w & 0xffffu); a7 += bf2f(v0.w >> 16);
    }
#define CMB(a) a += __shfl_xor(a, 32); a += __shfl_xor(a, 16);
    CMB(a0) CMB(a1) CMB(a2) CMB(a3) CMB(a4) CMB(a5) CMB(a6) CMB(a7)
#undef CMB
    if (lane < 16) {
        float id = 1.0f / fmaxf((float)(end - beg), 1.0f);
        ushort p[8];
        p[0] = f2bf(a0 * id); p[1] = f2bf(a1 * id);
        p[2] = f2bf(a2 * id); p[3] = f2bf(a3 * id);
        p[4] = f2bf(a4 * id); p[5] = f2bf(a5 * id);
        p[6] = f2bf(a6 * id); p[7] = f2bf(a7 * id);
        *(uint4*)&mean[(size_t)node * 128 + l * 8] = *(uint4*)p;
    }
}

// ---------------- weight prep: fp32 -> bf16, concat [Wl|Wr] ----------------
__global__ __launch_bounds__(256) void prep_w(const float* __restrict__ W1l,
                                              const float* __restrict__ W1r,
                                              const float* __restrict__ Wlin,
                                              const float* __restrict__ W2l,
                                              const float* __restrict__ W2r,
                                              ushort* __restrict__ Wcat1,
                                              ushort* __restrict__ Wlinb,
                                              ushort* __restrict__ Wcat2) {
    int i = blockIdx.x * 256 + threadIdx.x;
    if (i < 65536) {               // Wcat1 [256][256]
        int o = i >> 8, k = i & 255;
        float v = (k < 128) ? W1l[o * 128 + k] : W1r[o * 128 + k - 128];
        Wcat1[i] = f2bf(v);
    } else if (i < 98304) {        // Wlin [128][256]
        int j = i - 65536;
        Wlinb[j] = f2bf(Wlin[j]);
    } else {                       // Wcat2 [128][256]
        int j = i - 98304;
        int o = j >> 8, k = j & 255;
        float v = (k < 128) ? W2l[o * 128 + k] : W2r[o * 128 + k - 128];
        Wcat2[j] = f2bf(v);
    }
}

// ---------------- x fp32 -> bf16 ----------------
__global__ __launch_bounds__(256) void xcvt(const float* __restrict__ x,
                                            ushort* __restrict__ xbf) {
    int i = blockIdx.x * 256 + threadIdx.x;
    float4 v = ((const float4*)x)[i];
    ushort4 p;
    p.x = f2bf(v.x); p.y = f2bf(v.y); p.z = f2bf(v.z); p.w = f2bf(v.w);
    ((ushort4*)xbf)[i] = p;
}

// --- conv1+linear fused: h = l2norm([mean|x]@Wcat1^T + b1), hr = relu(h@Wlin^T + blin)
__global__ __launch_bounds__(256) void conv1lin_mfma(const ushort* __restrict__ mean,
                                                     const ushort* __restrict__ xbf,
                                                     const ushort* __restrict__ Wcat,
                                                     const float* __restrict__ bias1,
                                                     const ushort* __restrict__ Wlin,
                                                     const float* __restrict__ blin,
                                                     ushort* __restrict__ hr) {
    __shared__ char As[64 * 512];
    __shared__ char Bs[64 * 512];
    int m0 = blockIdx.x * 64;
    int tid = threadIdx.x;
    for (int c = tid; c < 2048; c += 256) {
        int m = c >> 5, kc = c & 31;
        int mm = min(m0 + m, NN - 1);
        uint4 v = (kc < 16) ? *(const uint4*)&mean[(size_t)mm * 128 + kc * 8]
                            : *(const uint4*)&xbf[(size_t)mm * 128 + (kc - 16) * 8];
        *(uint4*)(As + swz(m * 512 + kc * 16)) = v;
    }
    for (int j = tid; j < 2048; j += 256)
        *(uint4*)(Bs + swz((j >> 5) * 512 + (j & 31) * 16)) = *(const uint4*)&Wcat[j * 8];
    __syncthreads();

    int lane = tid & 63, wave = tid >> 6;
    int col = lane & 15, kg = lane >> 4;
    int mym = wave * 16 + col;
    short8 a[8];
#pragma unroll
    for (int ks = 0; ks < 8; ++ks)
        a[ks] = *(const short8*)(As + swz(mym * 512 + (ks * 32 + kg * 8) * 2));
    f32x4 acc[16];
#pragma unroll
    for (int nt = 0; nt < 4; ++nt) {
        f32x4 c = {0.f, 0.f, 0.f, 0.f};
#pragma unroll
        for (int ks = 0; ks < 8; ++ks)
            c = __builtin_amdgcn_mfma_f32_16x16x32_bf16(
                a[ks], *(const short8*)(Bs + swz((nt * 16 + col) * 512 + (ks * 32 + kg * 8) * 2)), c, 0, 0, 0);
        acc[nt] = c;
    }
    for (int ch = 1; ch < 4; ++ch) {
        __syncthreads();
        for (int j = tid; j < 2048; j += 256)
            *(uint4*)(Bs + swz((j >> 5) * 512 + (j & 31) * 16)) =
                *(const uint4*)&Wcat[ch * 16384 + j * 8];
        __syncthreads();
#pragma unroll
        for (int nt = 0; nt < 4; ++nt) {
            f32x4 c = {0.f, 0.f, 0.f, 0.f};
#pragma unroll
            for (int ks = 0; ks < 8; ++ks)
                c = __builtin_amdgcn_mfma_f32_16x16x32_bf16(
                    a[ks], *(const short8*)(Bs + swz((nt * 16 + col) * 512 + (ks * 32 + kg * 8) * 2)), c, 0, 0, 0);
            acc[ch * 4 + nt] = c;
        }
    }
    // bias + l2norm
    float ssq[4] = {0.f, 0.f, 0.f, 0.f};
#pragma unroll
    for (int nt = 0; nt < 16; ++nt) {
        float b = bias1[nt * 16 + col];
#pragma unroll
        for (int r = 0; r < 4; ++r) {
            acc[nt][r] += b;
            ssq[r] += acc[nt][r] * acc[nt][r];
        }
    }
#pragma unroll
    for (int off = 1; off < 16; off <<= 1)
#pragma unroll
        for (int r = 0; r < 4; ++r) ssq[r] += __shfl_xor(ssq[r], off);
    float rn[4];
#pragma unroll
    for (int r = 0; r < 4; ++r) rn[r] = 1.0f / fmaxf(sqrtf(ssq[r]), 1e-12f);
    // write h (bf16) into As, swizzled rows
#pragma unroll
    for (int r = 0; r < 4; ++r) {
        int rl = wave * 16 + kg * 4 + r;
#pragma unroll
        for (int nt = 0; nt < 16; ++nt)
            *(ushort*)(As + swz(rl * 512 + (nt * 16 + col) * 2)) = f2bf(acc[nt][r] * rn[r]);
    }
    __syncthreads();   // h complete; also guarantees all Bs(Wcat) reads done
    // second GEMM: hr = relu(h @ Wlin^T + blin)
    short8 a2[8];
#pragma unroll
    for (int ks = 0; ks < 8; ++ks)
        a2[ks] = *(const short8*)(As + swz(mym * 512 + (ks * 32 + kg * 8) * 2));
    for (int j = tid; j < 2048; j += 256)
        *(uint4*)(Bs + swz((j >> 5) * 512 + (j & 31) * 16)) = *(const uint4*)&Wlin[j * 8];
    __syncthreads();
    f32x4 acc2[8];
#pragma unroll
    for (int nt = 0; nt < 4; ++nt) {
        f32x4 c = {0.f, 0.f, 0.f, 0.f};
#pragma unroll
        for (int ks = 0; ks < 8; ++ks)
            c = __builtin_amdgcn_mfma_f32_16x16x32_bf16(
                a2[ks], *(const short8*)(Bs + swz((nt * 16 + col) * 512 + (ks * 32 + kg * 8) * 2)), c, 0, 0, 0);
        acc2[nt] = c;
    }
    __syncthreads();
    for (int j = tid; j < 2048; j += 256)
        *(uint4*)(Bs + swz((j >> 5) * 512 + (j & 31) * 16)) = *(const uint4*)&Wlin[16384 + j * 8];
    __syncthreads();
#pragma unroll
    for (int nt = 0; nt < 4; ++nt) {
        f32x4 c = {0.f, 0.f, 0.f, 0.f};
#pragma unroll
        for (int ks = 0; ks < 8; ++ks)
            c = __builtin_amdgcn_mfma_f32_16x16x32_bf16(
                a2[ks], *(const short8*)(Bs + swz((nt * 16 + col) * 512 + (ks * 32 + kg * 8) * 2)), c, 0, 0, 0);
        acc2[4 + nt] = c;
    }
#pragma unroll
    for (int r = 0; r < 4; ++r) {
        int node = m0 + wave * 16 + kg * 4 + r;
        if (node < NN) {
#pragma unroll
            for (int nt = 0; nt < 8; ++nt) {
                float vv = acc2[nt][r] + blin[nt * 16 + col];
                hr[(size_t)node * 128 + nt * 16 + col] = f2bf(fmaxf(vv, 0.f));
            }
        }
    }
}

// ------- conv2 + linear2 + softmax: y = l2norm([mean2|hr]@Wcat2^T + b2l) -----
__global__ __launch_bounds__(256) void conv2_mfma(const ushort* __restrict__ mean,
                                                  const ushort* __restrict__ hr,
                                                  const ushort* __restrict__ Wcat,
                                                  const float* __restrict__ bias,
                                                  const float* __restrict__ Wlin2,
                                                  const float* __restrict__ blin2,
                                                  float* __restrict__ probs,
                                                  float* __restrict__ yout) {
    __shared__ char As[64 * 512];
    __shared__ char Bs[64 * 512];
    int m0 = blockIdx.x * 64;
    int tid = threadIdx.x;
    for (int c = tid; c < 2048; c += 256) {
        int m = c >> 5, kc = c & 31;
        int mm = min(m0 + m, NN - 1);
        uint4 v = (kc < 16) ? *(const uint4*)&mean[(size_t)mm * 128 + kc * 8]
                            : *(const uint4*)&hr[(size_t)mm * 128 + (kc - 16) * 8];
        *(uint4*)(As + swz(m * 512 + kc * 16)) = v;
    }
    for (int j = tid; j < 2048; j += 256)
        *(uint4*)(Bs + swz((j >> 5) * 512 + (j & 31) * 16)) = *(const uint4*)&Wcat[j * 8];
    __syncthreads();

    int lane = tid & 63, wave = tid >> 6;
    int col = lane & 15, kg = lane >> 4;
    int mym = wave * 16 + col;
    short8 a[8];
#pragma unroll
    for (int ks = 0; ks < 8; ++ks)
        a[ks] = *(const short8*)(As + swz(mym * 512 + (ks * 32 + kg * 8) * 2));
    f32x4 acc[8];
#pragma unroll
    for (int nt = 0; nt < 4; ++nt) {
        f32x4 c = {0.f, 0.f, 0.f, 0.f};
#pragma unroll
        for (int ks = 0; ks < 8; ++ks)
            c = __builtin_amdgcn_mfma_f32_16x16x32_bf16(
                a[ks], *(const short8*)(Bs + swz((nt * 16 + col) * 512 + (ks * 32 + kg * 8) * 2)), c, 0, 0, 0);
        acc[nt] = c;
    }
    __syncthreads();
    for (int j = tid; j < 2048; j += 256)
        *(uint4*)(Bs + swz((j >> 5) * 512 + (j & 31) * 16)) = *(const uint4*)&Wcat[16384 + j * 8];
    __syncthreads();
#pragma unroll
    for (int nt = 0; nt < 4; ++nt) {
        f32x4 c = {0.f, 0.f, 0.f, 0.f};
#pragma unroll
        for (int ks = 0; ks < 8; ++ks)
            c = __builtin_amdgcn_mfma_f32_16x16x32_bf16(
                a[ks], *(const short8*)(Bs + swz((nt * 16 + col) * 512 + (ks * 32 + kg * 8) * 2)), c, 0, 0, 0);
        acc[4 + nt] = c;
    }
    float ssq[4] = {0.f, 0.f, 0.f, 0.f};
#pragma unroll
    for (int nt = 0; nt < 8; ++nt) {
        float b = bias[nt * 16 + col];
#pragma unroll
        for (int r = 0; r < 4; ++r) {
            acc[nt][r] += b;
            ssq[r] += acc[nt][r] * acc[nt][r];
        }
    }
#pragma unroll
    for (int off = 1; off < 16; off <<= 1)
#pragma unroll
        for (int r = 0; r < 4; ++r) ssq[r] += __shfl_xor(ssq[r], off);
    float rn[4], p0[4] = {0.f,0.f,0.f,0.f}, p1[4] = {0.f,0.f,0.f,0.f};
#pragma unroll
    for (int r = 0; r < 4; ++r) rn[r] = 1.0f / fmaxf(sqrtf(ssq[r]), 1e-12f);
#pragma unroll
    for (int nt = 0; nt < 8; ++nt) {
        float w0 = Wlin2[nt * 16 + col], w1 = Wlin2[128 + nt * 16 + col];
#pragma unroll
        for (int r = 0; r < 4; ++r) {
            float yv = acc[nt][r] * rn[r];
            acc[nt][r] = yv;
            p0[r] += yv * w0;
            p1[r] += yv * w1;
        }
    }
#pragma unroll
    for (int off = 1; off < 16; off <<= 1)
#pragma unroll
        for (int r = 0; r < 4; ++r) { p0[r] += __shfl_xor(p0[r], off); p1[r] += __shfl_xor(p1[r], off); }
#pragma unroll
    for (int r = 0; r < 4; ++r) {
        int node = m0 + wave * 16 + kg * 4 + r;
        if (node < NN) {
#pragma unroll
            for (int nt = 0; nt < 8; ++nt)
                yout[(size_t)node * 128 + nt * 16 + col] = acc[nt][r];
            if (col == 0) {
                float l0 = p0[r] + blin2[0], l1 = p1[r] + blin2[1];
                float mx = fmaxf(l0, l1);
                float e0 = expf(l0 - mx), e1 = expf(l1 - mx);
                float inv = 1.0f / (e0 + e1);
                probs[(size_t)node * 2 + 0] = e0 * inv;
                probs[(size_t)node * 2 + 1] = e1 * inv;
            }
        }
    }
}

extern "C" void kernel_launch(void* const* d_in, const int* in_sizes, int n_in,
                              void* d_out, int out_size, void* d_ws, size_t ws_size,
                              hipStream_t stream) {
    const float* x     = (const float*)d_in[0];
    const int*   ei    = (const int*)d_in[1];
    const int*   src   = ei;
    const int*   tgt   = ei + NE;
    const float* W1l   = (const float*)d_in[2];
    const float* b1l   = (const float*)d_in[3];
    const float* W1r   = (const float*)d_in[4];
    const float* Wlin  = (const float*)d_in[5];
    const float* blin  = (const float*)d_in[6];
    const float* W2l   = (const float*)d_in[7];
    const float* b2l   = (const float*)d_in[8];
    const float* W2r   = (const float*)d_in[9];
    const float* Wlin2 = (const float*)d_in[10];
    const float* blin2 = (const float*)d_in[11];

    float* probs = (float*)d_out;              // [N,2]
    float* y     = (float*)d_out + 2 * NN;     // [N,128]

    // ws layout
    int*    bcnt      = (int*)d_ws;                     // NBK
    int*    bbase     = bcnt + NBK;                     // NBK+1
    int*    bcursor   = bbase + NBK + 1;                // NBK
    int*    rowstart  = bcursor + NBK;                  // NN+1
    uint*   brec      = (uint*)(rowstart + NN + 1);     // NE
    int*    sortedSrc = (int*)(brec + NE);              // NE
    ushort* Wcat1     = (ushort*)(sortedSrc + NE);      // 256*256
    ushort* Wlinb     = Wcat1 + 65536;                  // 128*256
    ushort* Wcat2     = Wlinb + 32768;                  // 128*256
    ushort* xbf       = Wcat2 + 32768;                  // N*128 (later hr)
    ushort* mean      = xbf + (size_t)NN * 128;         // N*128
    ushort* hr        = xbf;                            // alias: safe, per-block row ownership

    const int NEB = (NE + EPB - 1) / EPB;               // 196 edge blocks

    hipMemsetAsync(bcnt, 0, sizeof(int) * NBK, stream);

    prep_w<<<512, 256, 0, stream>>>(W1l, W1r, Wlin, W2l, W2r, Wcat1, Wlinb, Wcat2);
    xcvt<<<NN * 32 / 256, 256, 0, stream>>>(x, xbf);

    bucket_hist<<<NEB, 256, 0, stream>>>(tgt, bcnt);
    bucket_scan<<<1, 256, 0, stream>>>(bcnt, bbase, bcursor, rowstart);
    bucket_scatter<<<NEB, 256, 0, stream>>>(src, tgt, bcursor, brec);
    bucket_to_csr<<<NBK, 256, 0, stream>>>(brec, bbase, rowstart, sortedSrc);

    gather_mean<<<(NN + 3) / 4, 256, 0, stream>>>(xbf, rowstart, sortedSrc, mean);
    conv1lin_mfma<<<(NN + 63) / 64, 256, 0, stream>>>(mean, xbf, Wcat1, b1l,
                                                      Wlinb, blin, hr);
    gather_mean<<<(NN + 3) / 4, 256, 0, stream>>>(hr, rowstart, sortedSrc, mean);
    conv2_mfma<<<(NN + 63) / 64, 256, 0, stream>>>(mean, hr, Wcat2, b2l,
                                                   Wlin2, blin2, probs, y);
}